// Round 11
// baseline (297.311 us; speedup 1.0000x reference)
//
#include <hip/hip_runtime.h>

#define B_ 4
#define L_ 2048
#define D_ 1024
#define M_FLAT (B_*L_)   // 8192
#define NE_ ((size_t)M_FLAT * D_)   // 8388608
#define WE_ ((size_t)D_ * D_)       // 1048576

typedef unsigned short bf16_t;
typedef __attribute__((ext_vector_type(8))) short bf16x8;
typedef __attribute__((ext_vector_type(4))) float f32x4;

__device__ __forceinline__ bf16_t f2bf(float f) {
  union { float f; unsigned int u; } c; c.f = f;
  unsigned int u = c.u;
  unsigned int r = (u + 0x7fffu + ((u >> 16) & 1u)) >> 16;
  return (bf16_t)r;
}
__device__ __forceinline__ float bf2f(bf16_t h) {
  union { unsigned int u; float f; } c; c.u = ((unsigned int)h) << 16;
  return c.f;
}

__device__ __forceinline__ void gload_lds16(const void* g, void* l) {
  __builtin_amdgcn_global_load_lds(
      (const __attribute__((address_space(1))) unsigned int*)g,
      (__attribute__((address_space(3))) unsigned int*)l, 16, 0, 0);
}

#define BARRIER() do { asm volatile("" ::: "memory"); \
                       __builtin_amdgcn_s_barrier();  \
                       asm volatile("" ::: "memory"); } while (0)

// ---- weight prep: z=0,1,2 transpose-cvt (Wq,Wk,Wo); z=3 straight cvt Wv ----
__global__ __launch_bounds__(256) void transpose_cvt4(const float* __restrict__ Wq,
                                                      const float* __restrict__ Wk,
                                                      const float* __restrict__ Wo,
                                                      const float* __restrict__ Wv,
                                                      bf16_t* __restrict__ outbase) {
  __shared__ float t[32][33];
  int zz = blockIdx.z;
  int c0 = blockIdx.x * 32, r0 = blockIdx.y * 32;
  int tx = threadIdx.x, ty = threadIdx.y;   // block (32,8)
  if (zz == 3) {   // Wv -> WVb (straight convert)
    bf16_t* o = outbase + 4 * WE_;
#pragma unroll
    for (int i = 0; i < 4; i++) {
      size_t idx = (size_t)(r0 + ty + i * 8) * D_ + c0 + tx;
      o[idx] = f2bf(Wv[idx]);
    }
    return;
  }
  const float* Wsrc = (zz == 0) ? Wq : (zz == 1) ? Wk : Wo;
  bf16_t* Wt = outbase + (size_t)(zz == 2 ? 3 : zz) * WE_;  // WQT,WKT,[W2T],WOT
#pragma unroll
  for (int i = 0; i < 4; i++)
    t[ty + i * 8][tx] = Wsrc[(size_t)(r0 + ty + i * 8) * D_ + c0 + tx];
  __syncthreads();
#pragma unroll
  for (int i = 0; i < 4; i++)
    Wt[(size_t)(c0 + ty + i * 8) * D_ + r0 + tx] = f2bf(t[tx][ty + i * 8]);
}

// ---- c2 = bv . Wo  (row vector, 1024) ----
__global__ __launch_bounds__(256) void c2_kernel(const float* __restrict__ bv,
                                                 const float* __restrict__ Wo,
                                                 float* __restrict__ c2) {
  int j = blockIdx.x * 256 + threadIdx.x;  // 1024
  float s = 0.f;
  for (int k = 0; k < D_; k++) s += bv[k] * Wo[(size_t)k * D_ + j];
  c2[j] = s;
}

// ---- pack int32 mask -> 1 bit/elem (64 ints -> one u64 via ballot) ----
__global__ __launch_bounds__(256) void pack_mask(const int* __restrict__ mask,
                                                 unsigned long long* __restrict__ bm) {
  size_t gid = (size_t)blockIdx.x * 256 + threadIdx.x;
  int mi = mask[gid];
  unsigned long long b = __ballot(mi != 0);
  if ((threadIdx.x & 63) == 0) bm[gid >> 6] = b;
}

// ---- reduce 32 rowsum partials -> rsum (guarded) ----
__global__ __launch_bounds__(256) void reduce_rsum(const float* __restrict__ rsp,
                                                   float* __restrict__ rs) {
  int r = blockIdx.x * 256 + threadIdx.x;   // 8192 rows
  float s = 0.f;
#pragma unroll
  for (int j = 0; j < 32; j++) s += rsp[(size_t)r * 32 + j];
  rs[r] = fmaxf(s, 1e-30f);
}

// ---- sum 8 fp32 K-split partials of W2, transpose+cvt -> W2T bf16 ----
__global__ __launch_bounds__(256) void w2_reduce(const float* __restrict__ pw,
                                                 bf16_t* __restrict__ w2t) {
  __shared__ float t[32][33];
  int c0 = blockIdx.x * 32, r0 = blockIdx.y * 32;
  int tx = threadIdx.x, ty = threadIdx.y;   // block (32,8)
#pragma unroll
  for (int i = 0; i < 4; i++) {
    size_t idx = (size_t)(r0 + ty + i * 8) * D_ + c0 + tx;
    float s = 0.f;
#pragma unroll
    for (int zz = 0; zz < 8; zz++) s += pw[(size_t)zz * WE_ + idx];
    t[ty + i * 8][tx] = s;
  }
  __syncthreads();
#pragma unroll
  for (int i = 0; i < 4; i++)
    w2t[(size_t)(c0 + ty + i * 8) * D_ + r0 + tx] = f2bf(t[tx][ty + i * 8]);
}

// ============ BMx256 BK=64 GEMM, free-running halves + counted vmcnt =========
// C = A(MxK) * Bt(NxK)^T.  8 waves (2M x 4N), 512 threads, 2 K-steps/iter.
// bf16 LDS swizzle: elem (r,k) at byte r*128 + ((k>>3)^(r&7))*16 + (k&7)*2.
// MODE_PROJ: A is fp32 (query/key/value direct) staged via global_load_lds
//   into an fp32 LDS region [64 rows][16 chunks x 16B], chunk ^= row&15
//   (pre-swizzled source, linear dest); LOAD_A does 2x ds_read_b128 + cvt.
//   Full-iteration prefetch slack preserved (the r10 reg-path failure mode).
#define MODE_PROJ 0  // z=0: Q=(acc+bq)/32; z=1: K=acc+bk; z=2: VW+c2 -> VWt (transposed)
#define MODE_S    1  // P = maskbit ? exp(acc) : 0 (bf16) + partial rowsums
#define MODE_FIN  2  // fp32 out = acc/rs[r] + bias[c]
#define MODE_TRK  3  // K-split fp32 partials (W2), z = K-chunk via strA=128

template <int BM, int MODE>
__global__ __launch_bounds__(512, 2)
void g8(const bf16_t* __restrict__ Abase, int lda, long strA,
        const bf16_t* __restrict__ Bbase, int ldb, long strB,
        void* __restrict__ outp, long strO, int ldo,
        const float* __restrict__ x0, const float* __restrict__ x1,
        const float* __restrict__ x2,
        const void* __restrict__ auxp, float* __restrict__ rsp,
        const float* __restrict__ fq, const float* __restrict__ fk,
        const float* __restrict__ fv,
        int K) {
  constexpr bool AF32 = (MODE == MODE_PROJ);
  constexpr int WROWS = BM / 2;             // per m-wave rows (= A-half rows)
  constexpr int QAF   = WROWS / 32;         // frag-rows per A-quadrant
  constexpr int MFR   = WROWS / 16;         // acc rows
  constexpr int ROWBA = AF32 ? 256 : 128;   // A bytes per row in LDS
  constexpr int AHB   = WROWS * ROWBA;      // bytes per A-half
  constexpr int ALH   = AHB / 8192;         // gload issues per A-half
  constexpr int BUFB  = BM * ROWBA + 256 * 128;
  constexpr int EPB   = WROWS * 128;        // epilogue restage tile per wave
  constexpr int TIN   = 4 + 2 * ALH;        // vmem instrs per staged K-tile
  extern __shared__ __align__(16) char smem[];

  const int tid = threadIdx.x, lane = tid & 63, w = tid >> 6;
  const int wm = w >> 2, wn = w & 3;
  const int fr = lane & 15, fs = lane >> 4;
  const int z = blockIdx.z;

  // XCD-chunk swizzle over (x,y) plane; z untouched
  int gx = gridDim.x, nxy = gx * gridDim.y;
  int lin = blockIdx.y * gx + blockIdx.x;
  if ((nxy & 7) == 0) { int q = nxy >> 3; lin = (lin & 7) * q + (lin >> 3); }
  const int xb = lin % gx;
  const int mbase = (lin / gx) * BM, nbase = xb * 256;

  const bf16_t* A  = Abase + (size_t)z * strA;
  const bf16_t* Bt = Bbase + (size_t)z * strB;
  const float* FA = AF32 ? ((z == 0) ? fq : (z == 1) ? fk : fv) : nullptr;

  int offA[2][2], offB[2][2];
#pragma unroll
  for (int h = 0; h < 2; h++)
#pragma unroll
    for (int i = 0; i < 2; i++) {
      if constexpr (AF32) {
        int c = i * 512 + tid, r = c >> 4, ch = c & 15;
        if (i < ALH) offA[h][i] = (mbase + h * WROWS + r) * lda + (ch ^ (r & 15)) * 4;
      } else {
        int c = i * 512 + tid, row = c >> 3;
        int sg = (c & 7) ^ (row & 7);
        if (i < ALH) offA[h][i] = (mbase + h * WROWS + row) * lda + sg * 8;
      }
      int c = i * 512 + tid, row = c >> 3;
      int sg = (c & 7) ^ (row & 7);
      offB[h][i] = (nbase + h * 128 + row) * ldb + sg * 8;
    }

  const int swz0 = (fs ^ (fr & 7)) * 16;
  const int swz1 = ((4 + fs) ^ (fr & 7)) * 16;

  bf16x8 af[QAF][2], bfv[2][2][2];
  f32x4 acc[MFR][4] = {};

#define STAGE_A(h, kt, bsel) do {                                             \
    char* hb_ = smem + (bsel) * BUFB + (h) * AHB;                             \
    _Pragma("unroll")                                                         \
    for (int i_ = 0; i_ < ALH; ++i_) {                                        \
      if constexpr (AF32)                                                     \
        gload_lds16(FA + offA[h][i_] + (kt) * 64, hb_ + (i_ * 512 + tid) * 16); \
      else                                                                    \
        gload_lds16(A + offA[h][i_] + (kt) * 64, hb_ + (i_ * 512 + tid) * 16); \
    }                                                                         \
  } while (0)
#define STAGE_B(h, kt, bsel) do {                                             \
    char* hb_ = smem + (bsel) * BUFB + BM * ROWBA + (h) * 16384;              \
    _Pragma("unroll")                                                         \
    for (int i_ = 0; i_ < 2; ++i_)                                            \
      gload_lds16(Bt + offB[h][i_] + (kt) * 64, hb_ + (i_ * 512 + tid) * 16); \
  } while (0)
#define LOAD_A(bsel, mh) do {                                                 \
    if constexpr (AF32) {                                                     \
      const char* ab_ = smem + (bsel) * BUFB + wm * AHB;                      \
      _Pragma("unroll")                                                       \
      for (int i_ = 0; i_ < QAF; ++i_) {                                      \
        int row_ = (mh) * (WROWS / 2) + i_ * 16 + fr;                         \
        _Pragma("unroll")                                                     \
        for (int kk_ = 0; kk_ < 2; ++kk_) {                                   \
          float4 u0_ = *(const float4*)(ab_ + row_ * 256 +                    \
              (((kk_ * 8 + fs * 2 + 0) ^ (row_ & 15)) * 16));                 \
          float4 u1_ = *(const float4*)(ab_ + row_ * 256 +                    \
              (((kk_ * 8 + fs * 2 + 1) ^ (row_ & 15)) * 16));                 \
          union { bf16_t hh[8]; bf16x8 v; } cv_;                              \
          cv_.hh[0] = f2bf(u0_.x); cv_.hh[1] = f2bf(u0_.y);                   \
          cv_.hh[2] = f2bf(u0_.z); cv_.hh[3] = f2bf(u0_.w);                   \
          cv_.hh[4] = f2bf(u1_.x); cv_.hh[5] = f2bf(u1_.y);                   \
          cv_.hh[6] = f2bf(u1_.z); cv_.hh[7] = f2bf(u1_.w);                   \
          af[i_][kk_] = cv_.v;                                                \
        }                                                                     \
      }                                                                       \
    } else {                                                                  \
      const char* ab_ = smem + (bsel) * BUFB + (wm * WROWS) * 128;            \
      _Pragma("unroll")                                                       \
      for (int i_ = 0; i_ < QAF; ++i_) {                                      \
        int rb_ = ((mh) * (WROWS / 2) + i_ * 16 + fr) * 128;                  \
        af[i_][0] = *(const bf16x8*)(ab_ + rb_ + swz0);                       \
        af[i_][1] = *(const bf16x8*)(ab_ + rb_ + swz1);                       \
      }                                                                       \
    }                                                                         \
  } while (0)
#define LOAD_B(bsel, nh) do {                                                 \
    const char* bb_ = smem + (bsel) * BUFB + BM * ROWBA + (wn * 64) * 128;    \
    _Pragma("unroll")                                                         \
    for (int j_ = 0; j_ < 2; ++j_) {                                          \
      int rb_ = ((nh) * 32 + j_ * 16 + fr) * 128;                             \
      bfv[nh][j_][0] = *(const bf16x8*)(bb_ + rb_ + swz0);                    \
      bfv[nh][j_][1] = *(const bf16x8*)(bb_ + rb_ + swz1);                    \
    }                                                                         \
  } while (0)
#define MFMA_Q(mh, nh) do {                                                   \
    __builtin_amdgcn_s_setprio(1);                                            \
    _Pragma("unroll")                                                         \
    for (int i_ = 0; i_ < QAF; ++i_)                                          \
    _Pragma("unroll")                                                         \
    for (int j_ = 0; j_ < 2; ++j_) {                                          \
      acc[(mh)*QAF + i_][(nh)*2 + j_] = __builtin_amdgcn_mfma_f32_16x16x32_bf16( \
          af[i_][0], bfv[nh][j_][0], acc[(mh)*QAF + i_][(nh)*2 + j_], 0, 0, 0);  \
      acc[(mh)*QAF + i_][(nh)*2 + j_] = __builtin_amdgcn_mfma_f32_16x16x32_bf16( \
          af[i_][1], bfv[nh][j_][1], acc[(mh)*QAF + i_][(nh)*2 + j_], 0, 0, 0);  \
    }                                                                         \
    __builtin_amdgcn_s_setprio(0);                                            \
  } while (0)
#define VMWN() do {                                                           \
    if constexpr (TIN == 8) asm volatile("s_waitcnt vmcnt(8)" ::: "memory");  \
    else                    asm volatile("s_waitcnt vmcnt(6)" ::: "memory");  \
  } while (0)
#define LGKM0() asm volatile("s_waitcnt lgkmcnt(0)" ::: "memory")

  const int NK = K >> 6, NI = NK >> 1;

  // prologue: t0 -> buf0 ; t1 -> buf1 ; wait t0 landed (t1 in flight)
  STAGE_B(0, 0, 0); STAGE_B(1, 0, 0); STAGE_A(0, 0, 0); STAGE_A(1, 0, 0);
  STAGE_B(0, 1, 1); STAGE_B(1, 1, 1); STAGE_A(0, 1, 1); STAGE_A(1, 1, 1);
  VMWN(); BARRIER();

  for (int it = 0; it < NI; ++it) {
    const int ta = (2 * it + 2 < NK) ? 2 * it + 2 : NK - 1;
    const int tb = (2 * it + 3 < NK) ? 2 * it + 3 : NK - 1;
    // ---- first half: compute buf0 (t0), free-run ----
    LOAD_A(0, 0); LOAD_B(0, 0); MFMA_Q(0, 0);
    LOAD_B(0, 1);               MFMA_Q(0, 1);
    LOAD_A(0, 1);               MFMA_Q(1, 1);
                                MFMA_Q(1, 0);
    BARRIER();                       // all waves done reading buf0
    STAGE_B(0, ta, 0); STAGE_B(1, ta, 0); STAGE_A(0, ta, 0); STAGE_A(1, ta, 0);
    VMWN();                          // t1 landed (issued a full iter ago)
    BARRIER();
    // ---- second half: compute buf1 (t1), free-run ----
    LOAD_A(1, 0); LOAD_B(1, 0); MFMA_Q(0, 0);
    LOAD_B(1, 1);               MFMA_Q(0, 1);
    LOAD_A(1, 1);               MFMA_Q(1, 1);
                                MFMA_Q(1, 0);
    BARRIER();                       // all waves done reading buf1
    STAGE_B(0, tb, 1); STAGE_B(1, tb, 1); STAGE_A(0, tb, 1); STAGE_A(1, tb, 1);
    VMWN();                          // ta landed
    BARRIER();
  }
  asm volatile("s_waitcnt vmcnt(0)" ::: "memory");

  // ---- epilogues ----  C/D frag: col = fr, row = fs*4 + jj
  const int r0 = mbase + wm * WROWS;
  const int c0 = nbase + wn * 64;

  if constexpr (MODE == MODE_PROJ) {
    BARRIER();   // every wave drained -> LDS reusable
    char* ep = smem + w * EPB;
    if (z < 2) {   // row-major bf16 with bias+scale, coalesced via LDS restage
      bf16_t* o = (bf16_t*)outp + (size_t)z * strO;
      const float* bias = (z == 0) ? x0 : x1;
      const float scale = (z == 0) ? 0.03125f : 1.0f;
#pragma unroll
      for (int nf = 0; nf < 4; ++nf) {
        float bv = bias[c0 + nf * 16 + fr];
#pragma unroll
        for (int mf = 0; mf < MFR; ++mf)
#pragma unroll
          for (int jj = 0; jj < 4; ++jj) {
            int row = mf * 16 + fs * 4 + jj;
            int slot = (nf * 2 + (fr >> 3)) ^ ((row >> 1) & 7);
            *(bf16_t*)(ep + row * 128 + slot * 16 + (fr & 7) * 2) =
                f2bf((acc[mf][nf][jj] + bv) * scale);
          }
      }
      LGKM0();
      const int rl = lane >> 3, sl = lane & 7;
#pragma unroll
      for (int i = 0; i < WROWS / 8; ++i) {
        int row = i * 8 + rl;
        int slot = sl ^ ((row >> 1) & 7);
        uint4 vv = *(const uint4*)(ep + row * 128 + slot * 16);
        *(uint4*)&o[(size_t)(r0 + row) * ldo + c0 + sl * 8] = vv;
      }
    } else {   // z==2: VW + c2 -> VWt[b][c][r] transposed, coalesced
      bf16_t* ob = (bf16_t*)auxp;
      const int bidx = r0 >> 11, rb = r0 & (L_ - 1);
      ob += (size_t)bidx * D_ * L_;
#pragma unroll
      for (int nf = 0; nf < 4; ++nf) {
        int coll = nf * 16 + fr;
        float bv = x2[c0 + coll];
        int xm = (coll & (WROWS / 8 - 1)) << 3;
#pragma unroll
        for (int mf = 0; mf < MFR; ++mf) {
          int rbase = mf * 16 + fs * 4;
          union { bf16_t h[4]; uint2 u; } pk;
#pragma unroll
          for (int jj = 0; jj < 4; ++jj) pk.h[jj] = f2bf(acc[mf][nf][jj] + bv);
          *(uint2*)(ep + coll * (WROWS * 2) + 2 * (rbase ^ xm)) = pk.u;
        }
      }
      LGKM0();
      constexpr int LPC = WROWS / 8;
      constexpr int CPI = 64 / LPC;
      const int colr = lane / LPC;
      const int rc = (lane % LPC) * 8;
#pragma unroll
      for (int i2 = 0; i2 < LPC; ++i2) {
        int coll = i2 * CPI + colr;
        int xm = (coll & (WROWS / 8 - 1)) << 3;
        uint4 vv = *(const uint4*)(ep + coll * (WROWS * 2) + 2 * (rc ^ xm));
        *(uint4*)&ob[(size_t)(c0 + coll) * L_ + rb + rc] = vv;
      }
    }
  } else if constexpr (MODE == MODE_TRK) {   // fp32 K-split partials
    float* o = (float*)outp + (size_t)z * strO;
#pragma unroll
    for (int mf = 0; mf < MFR; ++mf) {
#pragma unroll
      for (int jj = 0; jj < 4; ++jj) {
        int r = r0 + mf * 16 + fs * 4 + jj;
#pragma unroll
        for (int nf = 0; nf < 4; ++nf)
          o[(size_t)r * ldo + c0 + nf * 16 + fr] = acc[mf][nf][jj];
      }
    }
  } else if constexpr (MODE == MODE_S) {
    BARRIER();
    char* ep = smem + w * EPB;
    bf16_t* o = (bf16_t*)outp + (size_t)z * strO;
    const unsigned long long* bw =
        (const unsigned long long*)auxp +
        ((size_t)z * L_ + r0) * 32 + (c0 >> 6);
#pragma unroll
    for (int mf = 0; mf < MFR; ++mf) {
#pragma unroll
      for (int jj = 0; jj < 4; ++jj) {
        int row = mf * 16 + fs * 4 + jj;
        unsigned long long wd = bw[(size_t)row * 32];
        float psum = 0.f;
#pragma unroll
        for (int nf = 0; nf < 4; ++nf) {
          int cbit = nf * 16 + fr;
          float e = ((wd >> cbit) & 1ull) ? __expf(acc[mf][nf][jj]) : 0.0f;
          bf16_t eb = f2bf(e);
          psum += bf2f(eb);
          int slot = (nf * 2 + (fr >> 3)) ^ ((row >> 1) & 7);
          *(bf16_t*)(ep + row * 128 + slot * 16 + (fr & 7) * 2) = eb;
        }
#pragma unroll
        for (int off = 8; off; off >>= 1) psum += __shfl_xor(psum, off, 16);
        if (fr == 0)
          rsp[((size_t)z * L_ + r0 + row) * 32 + xb * 4 + wn] = psum;
      }
    }
    LGKM0();
    const int rl = lane >> 3, sl = lane & 7;
#pragma unroll
    for (int i = 0; i < WROWS / 8; ++i) {
      int row = i * 8 + rl;
      int slot = sl ^ ((row >> 1) & 7);
      uint4 vv = *(const uint4*)(ep + row * 128 + slot * 16);
      *(uint4*)&o[(size_t)(r0 + row) * ldo + c0 + sl * 8] = vv;
    }
  } else {  // MODE_FIN — fp32 direct
    float* o = (float*)outp + (size_t)z * strO;
    const float* rs = x0 + (size_t)z * L_;
#pragma unroll
    for (int mf = 0; mf < MFR; ++mf) {
#pragma unroll
      for (int jj = 0; jj < 4; ++jj) {
        int r = r0 + mf * 16 + fs * 4 + jj;
        float inv = 1.0f / rs[r];
#pragma unroll
        for (int nf = 0; nf < 4; ++nf) {
          int c = c0 + nf * 16 + fr;
          o[(size_t)r * ldo + c] = acc[mf][nf][jj] * inv + x1[c];
        }
      }
    }
  }
#undef STAGE_A
#undef STAGE_B
#undef LOAD_A
#undef LOAD_B
#undef MFMA_Q
#undef VMWN
#undef LGKM0
}

extern "C" void kernel_launch(void* const* d_in, const int* in_sizes, int n_in,
                              void* d_out, int out_size, void* d_ws, size_t ws_size,
                              hipStream_t stream) {
  const float* query = (const float*)d_in[0];
  const float* keyi  = (const float*)d_in[1];
  const float* value = (const float*)d_in[2];
  const int*   mask  = (const int*)d_in[3];
  const float* Wq = (const float*)d_in[4];
  const float* bq = (const float*)d_in[5];
  const float* Wk = (const float*)d_in[6];
  const float* bk = (const float*)d_in[7];
  const float* Wv = (const float*)d_in[8];
  const float* bv = (const float*)d_in[9];
  const float* Wo = (const float*)d_in[10];
  const float* bo = (const float*)d_in[11];

  bf16_t* ws = (bf16_t*)d_ws;
  const size_t SBE = (size_t)B_ * L_ * L_;   // 16777216 elems (33.5 MB)
  bf16_t* Sb   = ws;                  // S/P (B,L,L)
  float*  pW2  = (float*)ws;          // 8 x WE_ fp32 = 32 MB, overlaps Sb (dead before S)
  bf16_t* WQT  = ws + SBE;            // WQT,WKT,W2T contiguous (PROJ B z-stride)
  bf16_t* WKT  = WQT + WE_;
  bf16_t* W2T  = WKT + WE_;
  bf16_t* WOT  = W2T + WE_;
  bf16_t* WVb  = WOT + WE_;
  bf16_t* Qb   = WVb + WE_;           // Qb,Kb contiguous (PROJ out z-stride)
  bf16_t* Kb   = Qb + NE_;
  bf16_t* VWt  = Kb + NE_;            // (B) x (D, L), written by PROJ z=2
  float*  rsump= (float*)(VWt + NE_);               // (B*L)
  float*  c2p  = rsump + (size_t)B_ * L_;           // (1024)
  float*  rspart = c2p + D_;                        // (B*L, 32)
  unsigned long long* bmask =
      (unsigned long long*)(rspart + (size_t)B_ * L_ * 32);  // (B*L*L/64)

  hipFuncSetAttribute((const void*)g8<128, MODE_PROJ>,
                      hipFuncAttributeMaxDynamicSharedMemorySize, 131072);
  hipFuncSetAttribute((const void*)g8<256, MODE_S>,
                      hipFuncAttributeMaxDynamicSharedMemorySize, 131072);
  hipFuncSetAttribute((const void*)g8<128, MODE_TRK>,
                      hipFuncAttributeMaxDynamicSharedMemorySize, 98304);
  hipFuncSetAttribute((const void*)g8<128, MODE_FIN>,
                      hipFuncAttributeMaxDynamicSharedMemorySize, 98304);

  // 1) prep: mask pack, weight transposes + Wv cvt, c2
  pack_mask<<<dim3(65536), dim3(256), 0, stream>>>(mask, bmask);
  transpose_cvt4<<<dim3(32, 32, 4), dim3(32, 8), 0, stream>>>(Wq, Wk, Wo, Wv, WQT);
  c2_kernel<<<dim3(4), dim3(256), 0, stream>>>(bv, Wo, c2p);
  // 2) W2 = Wv.Wo via K-split-8 (full 256-block round), fp32 partials
  g8<128, MODE_TRK><<<dim3(4, 8, 8), 512, 98304, stream>>>(
      WVb, D_, 128, WOT, D_, 128, pW2, (long)WE_, D_,
      nullptr, nullptr, nullptr, nullptr, nullptr,
      nullptr, nullptr, nullptr, 128);
  w2_reduce<<<dim3(32, 32), dim3(32, 8), 0, stream>>>(pW2, W2T);
  // 3) projections reading fp32 q/k/v via gload_lds (z: 0=Q, 1=K, 2=V.W2+c2)
  g8<128, MODE_PROJ><<<dim3(4, 64, 3), 512, 131072, stream>>>(
      nullptr, D_, 0, WQT, D_, (long)WE_, Qb, (long)NE_, D_,
      bq, bk, c2p, VWt, nullptr,
      query, keyi, value, D_);
  // 4) S = Q K^T fused with masked exp -> P (bf16) + partial rowsums
  g8<256, MODE_S><<<dim3(8, 8, 4), 512, 131072, stream>>>(
      Qb, D_, (long)L_ * D_, Kb, D_, (long)L_ * D_, Sb, (long)L_ * L_, L_,
      nullptr, nullptr, nullptr, bmask, rspart,
      nullptr, nullptr, nullptr, D_);
  // 5) reduce partial rowsums
  reduce_rsum<<<dim3(32), dim3(256), 0, stream>>>(rspart, rsump);
  // 6) out = (P . VWt^T)/rs + bo  -> fp32 d_out
  g8<128, MODE_FIN><<<dim3(4, 16, 4), 512, 98304, stream>>>(
      Sb, L_, (long)L_ * L_, VWt, L_, (long)D_ * L_, d_out, (long)L_ * D_, D_,
      rsump, bo, nullptr, nullptr, nullptr,
      nullptr, nullptr, nullptr, L_);
}

// Round 12
// 267.193 us; speedup vs baseline: 1.1127x; 1.1127x over previous
//
#include <hip/hip_runtime.h>

#define B_ 4
#define L_ 2048
#define D_ 1024
#define M_FLAT (B_*L_)   // 8192
#define NE_ ((size_t)M_FLAT * D_)   // 8388608
#define WE_ ((size_t)D_ * D_)       // 1048576

typedef unsigned short bf16_t;
typedef __attribute__((ext_vector_type(8))) short bf16x8;
typedef __attribute__((ext_vector_type(4))) float f32x4;

__device__ __forceinline__ bf16_t f2bf(float f) {
  union { float f; unsigned int u; } c; c.f = f;
  unsigned int u = c.u;
  unsigned int r = (u + 0x7fffu + ((u >> 16) & 1u)) >> 16;
  return (bf16_t)r;
}
__device__ __forceinline__ float bf2f(bf16_t h) {
  union { unsigned int u; float f; } c; c.u = ((unsigned int)h) << 16;
  return c.f;
}

__device__ __forceinline__ void gload_lds16(const bf16_t* g, bf16_t* l) {
  __builtin_amdgcn_global_load_lds(
      (const __attribute__((address_space(1))) unsigned int*)g,
      (__attribute__((address_space(3))) unsigned int*)l, 16, 0, 0);
}

#define BARRIER() do { asm volatile("" ::: "memory"); \
                       __builtin_amdgcn_s_barrier();  \
                       asm volatile("" ::: "memory"); } while (0)

// ---- merged fp32 -> bf16 converts: q,k,v -> XQ,XK,XV (contig) ----
__global__ __launch_bounds__(256) void prep_cvt(const float* __restrict__ q,
                                                const float* __restrict__ k,
                                                const float* __restrict__ v,
                                                bf16_t* __restrict__ xq) {
  const float* in; bf16_t* out; size_t li;
  int b = blockIdx.x;
  if (b < 4096)       { in = q;  out = xq;            li = (size_t)b * 256 + threadIdx.x; }
  else if (b < 8192)  { in = k;  out = xq + NE_;      li = (size_t)(b - 4096) * 256 + threadIdx.x; }
  else                { in = v;  out = xq + 2 * NE_;  li = (size_t)(b - 8192) * 256 + threadIdx.x; }
  const float4* p = (const float4*)in + li * 2;
  float4 a = p[0], bb = p[1];
  union { bf16_t h[8]; uint4 u; } r;
  r.h[0] = f2bf(a.x); r.h[1] = f2bf(a.y); r.h[2] = f2bf(a.z); r.h[3] = f2bf(a.w);
  r.h[4] = f2bf(bb.x); r.h[5] = f2bf(bb.y); r.h[6] = f2bf(bb.z); r.h[7] = f2bf(bb.w);
  ((uint4*)out)[li] = r.u;
}

// ---- weight prep: z=0,1,2 transpose-cvt (Wq,Wk,Wo); z=3 straight cvt Wv ----
__global__ __launch_bounds__(256) void transpose_cvt4(const float* __restrict__ Wq,
                                                      const float* __restrict__ Wk,
                                                      const float* __restrict__ Wo,
                                                      const float* __restrict__ Wv,
                                                      bf16_t* __restrict__ outbase) {
  __shared__ float t[32][33];
  int zz = blockIdx.z;
  int c0 = blockIdx.x * 32, r0 = blockIdx.y * 32;
  int tx = threadIdx.x, ty = threadIdx.y;   // block (32,8)
  if (zz == 3) {   // Wv -> WVb (straight convert)
    bf16_t* o = outbase + 4 * WE_;
#pragma unroll
    for (int i = 0; i < 4; i++) {
      size_t idx = (size_t)(r0 + ty + i * 8) * D_ + c0 + tx;
      o[idx] = f2bf(Wv[idx]);
    }
    return;
  }
  const float* Wsrc = (zz == 0) ? Wq : (zz == 1) ? Wk : Wo;
  bf16_t* Wt = outbase + (size_t)(zz == 2 ? 3 : zz) * WE_;  // WQT,WKT,[W2T],WOT
#pragma unroll
  for (int i = 0; i < 4; i++)
    t[ty + i * 8][tx] = Wsrc[(size_t)(r0 + ty + i * 8) * D_ + c0 + tx];
  __syncthreads();
#pragma unroll
  for (int i = 0; i < 4; i++)
    Wt[(size_t)(c0 + ty + i * 8) * D_ + r0 + tx] = f2bf(t[tx][ty + i * 8]);
}

// ---- c2 = bv . Wo  (row vector, 1024) ----
__global__ __launch_bounds__(256) void c2_kernel(const float* __restrict__ bv,
                                                 const float* __restrict__ Wo,
                                                 float* __restrict__ c2) {
  int j = blockIdx.x * 256 + threadIdx.x;  // 1024
  float s = 0.f;
  for (int k = 0; k < D_; k++) s += bv[k] * Wo[(size_t)k * D_ + j];
  c2[j] = s;
}

// ---- pack int32 mask -> 1 bit/elem (64 ints -> one u64 via ballot) ----
__global__ __launch_bounds__(256) void pack_mask(const int* __restrict__ mask,
                                                 unsigned long long* __restrict__ bm) {
  size_t gid = (size_t)blockIdx.x * 256 + threadIdx.x;
  int mi = mask[gid];
  unsigned long long b = __ballot(mi != 0);
  if ((threadIdx.x & 63) == 0) bm[gid >> 6] = b;
}

// ---- reduce 32 rowsum partials -> rsum (guarded) ----
__global__ __launch_bounds__(256) void reduce_rsum(const float* __restrict__ rsp,
                                                   float* __restrict__ rs) {
  int r = blockIdx.x * 256 + threadIdx.x;   // 8192 rows
  float s = 0.f;
#pragma unroll
  for (int j = 0; j < 32; j++) s += rsp[(size_t)r * 32 + j];
  rs[r] = fmaxf(s, 1e-30f);
}

// ---- sum 8 fp32 K-split partials of W2, transpose+cvt -> W2T bf16 ----
__global__ __launch_bounds__(256) void w2_reduce(const float* __restrict__ pw,
                                                 bf16_t* __restrict__ w2t) {
  __shared__ float t[32][33];
  int c0 = blockIdx.x * 32, r0 = blockIdx.y * 32;
  int tx = threadIdx.x, ty = threadIdx.y;   // block (32,8)
#pragma unroll
  for (int i = 0; i < 4; i++) {
    size_t idx = (size_t)(r0 + ty + i * 8) * D_ + c0 + tx;
    float s = 0.f;
#pragma unroll
    for (int zz = 0; zz < 8; zz++) s += pw[(size_t)zz * WE_ + idx];
    t[ty + i * 8][tx] = s;
  }
  __syncthreads();
#pragma unroll
  for (int i = 0; i < 4; i++)
    w2t[(size_t)(c0 + ty + i * 8) * D_ + r0 + tx] = f2bf(t[tx][ty + i * 8]);
}

// ============ BMx256 BK=64 GEMM, free-running halves + counted vmcnt =========
// C = A(MxK) * Bt(NxK)^T.  8 waves (2M x 4N), 512 threads, 2 K-steps/iter.
// LDS swizzle: elem (r,k) at byte r*128 + ((k>>3)^(r&7))*16 + (k&7)*2.
// Per iter: {compute buf0 free-run} BAR {stage t+2->buf0} VMWN BAR
//           {compute buf1 free-run} BAR {stage t+3->buf1} VMWN BAR
// (r8-proven structure; r10/r11 A-path experiments reverted.)
#define MODE_PROJ 0  // z=0: Q=(acc+bq)/32; z=1: K=acc+bk; z=2: VW+c2 -> VWt (transposed)
#define MODE_S    1  // P = maskbit ? exp(acc) : 0 (bf16) + partial rowsums
#define MODE_FIN  2  // fp32 out = acc/rs[r] + bias[c]
#define MODE_TRK  3  // K-split fp32 partials (W2), z = K-chunk via strA/strB=128

template <int BM, int MODE>
__global__ __launch_bounds__(512, 2)
void g8(const bf16_t* __restrict__ Abase, int lda, long strA,
        const bf16_t* __restrict__ Bbase, int ldb, long strB,
        void* __restrict__ outp, long strO, int ldo,
        const float* __restrict__ x0, const float* __restrict__ x1,
        const float* __restrict__ x2,
        const void* __restrict__ auxp, float* __restrict__ rsp,
        int K) {
  constexpr int WROWS = BM / 2;        // per m-wave rows
  constexpr int QAF   = WROWS / 32;    // frag-rows per A-quadrant
  constexpr int MFR   = WROWS / 16;    // acc rows
  constexpr int AL    = BM / 128;      // gloads per A-half
  constexpr int BL    = 2;             // gloads per B-half
  constexpr int AHB   = WROWS * 128;   // bytes per A-half (= per-wave epi tile)
  constexpr int BUFB  = (BM + 256) * 128;
  extern __shared__ __align__(16) char smem[];

  const int tid = threadIdx.x, lane = tid & 63, w = tid >> 6;
  const int wm = w >> 2, wn = w & 3;
  const int fr = lane & 15, fs = lane >> 4;
  const int z = blockIdx.z;

  // XCD-chunk swizzle over (x,y) plane; z untouched
  int gx = gridDim.x, nxy = gx * gridDim.y;
  int lin = blockIdx.y * gx + blockIdx.x;
  if ((nxy & 7) == 0) { int q = nxy >> 3; lin = (lin & 7) * q + (lin >> 3); }
  const int xb = lin % gx;
  const int mbase = (lin / gx) * BM, nbase = xb * 256;

  const bf16_t* A  = Abase + (size_t)z * strA;
  const bf16_t* Bt = Bbase + (size_t)z * strB;

  int offA[2][2], offB[2][2];
#pragma unroll
  for (int h = 0; h < 2; h++)
#pragma unroll
    for (int i = 0; i < 2; i++) {
      int c = i * 512 + tid, row = c >> 3;
      int sg = (c & 7) ^ (row & 7);
      if (i < AL) offA[h][i] = (mbase + h * WROWS + row) * lda + sg * 8;
      offB[h][i] = (nbase + h * 128 + row) * ldb + sg * 8;
    }

  const int swz0 = (fs ^ (fr & 7)) * 16;
  const int swz1 = ((4 + fs) ^ (fr & 7)) * 16;

  bf16x8 af[QAF][2], bfv[2][2][2];
  f32x4 acc[MFR][4] = {};

#define STAGE_A(h, kt, bsel) do {                                             \
    char* hb_ = smem + (bsel) * BUFB + (h) * AHB;                             \
    _Pragma("unroll")                                                         \
    for (int i_ = 0; i_ < AL; ++i_)                                           \
      gload_lds16(A + offA[h][i_] + (kt) * 64,                                \
                  (bf16_t*)(hb_ + (i_ * 512 + tid) * 16));                    \
  } while (0)
#define STAGE_B(h, kt, bsel) do {                                             \
    char* hb_ = smem + (bsel) * BUFB + BM * 128 + (h) * 16384;                \
    _Pragma("unroll")                                                         \
    for (int i_ = 0; i_ < BL; ++i_)                                           \
      gload_lds16(Bt + offB[h][i_] + (kt) * 64,                               \
                  (bf16_t*)(hb_ + (i_ * 512 + tid) * 16));                    \
  } while (0)
#define LOAD_A(bsel, mh) do {                                                 \
    const char* ab_ = smem + (bsel) * BUFB + (wm * WROWS) * 128;              \
    _Pragma("unroll")                                                         \
    for (int i_ = 0; i_ < QAF; ++i_) {                                        \
      int rb_ = ((mh) * (WROWS / 2) + i_ * 16 + fr) * 128;                    \
      af[i_][0] = *(const bf16x8*)(ab_ + rb_ + swz0);                         \
      af[i_][1] = *(const bf16x8*)(ab_ + rb_ + swz1);                         \
    }                                                                         \
  } while (0)
#define LOAD_B(bsel, nh) do {                                                 \
    const char* bb_ = smem + (bsel) * BUFB + BM * 128 + (wn * 64) * 128;      \
    _Pragma("unroll")                                                         \
    for (int j_ = 0; j_ < 2; ++j_) {                                          \
      int rb_ = ((nh) * 32 + j_ * 16 + fr) * 128;                             \
      bfv[nh][j_][0] = *(const bf16x8*)(bb_ + rb_ + swz0);                    \
      bfv[nh][j_][1] = *(const bf16x8*)(bb_ + rb_ + swz1);                    \
    }                                                                         \
  } while (0)
#define MFMA_Q(mh, nh) do {                                                   \
    __builtin_amdgcn_s_setprio(1);                                            \
    _Pragma("unroll")                                                         \
    for (int i_ = 0; i_ < QAF; ++i_)                                          \
    _Pragma("unroll")                                                         \
    for (int j_ = 0; j_ < 2; ++j_) {                                          \
      acc[(mh)*QAF + i_][(nh)*2 + j_] = __builtin_amdgcn_mfma_f32_16x16x32_bf16( \
          af[i_][0], bfv[nh][j_][0], acc[(mh)*QAF + i_][(nh)*2 + j_], 0, 0, 0);  \
      acc[(mh)*QAF + i_][(nh)*2 + j_] = __builtin_amdgcn_mfma_f32_16x16x32_bf16( \
          af[i_][1], bfv[nh][j_][1], acc[(mh)*QAF + i_][(nh)*2 + j_], 0, 0, 0);  \
    }                                                                         \
    __builtin_amdgcn_s_setprio(0);                                            \
  } while (0)
// leave exactly the just-issued tile (4 + 2*AL instrs) outstanding
#define VMWN() do {                                                           \
    if constexpr (AL == 2) asm volatile("s_waitcnt vmcnt(8)" ::: "memory");   \
    else                   asm volatile("s_waitcnt vmcnt(6)" ::: "memory");   \
  } while (0)
#define LGKM0() asm volatile("s_waitcnt lgkmcnt(0)" ::: "memory")

  const int NK = K >> 6, NI = NK >> 1;

  // prologue: t0 -> buf0 ; t1 -> buf1 ; wait t0 landed (t1 in flight)
  STAGE_B(0, 0, 0); STAGE_B(1, 0, 0); STAGE_A(0, 0, 0); STAGE_A(1, 0, 0);
  STAGE_B(0, 1, 1); STAGE_B(1, 1, 1); STAGE_A(0, 1, 1); STAGE_A(1, 1, 1);
  VMWN(); BARRIER();

  for (int it = 0; it < NI; ++it) {
    const int ta = (2 * it + 2 < NK) ? 2 * it + 2 : NK - 1;
    const int tb = (2 * it + 3 < NK) ? 2 * it + 3 : NK - 1;
    // ---- first half: compute buf0 (t0), free-run ----
    LOAD_A(0, 0); LOAD_B(0, 0); MFMA_Q(0, 0);
    LOAD_B(0, 1);               MFMA_Q(0, 1);
    LOAD_A(0, 1);               MFMA_Q(1, 1);
                                MFMA_Q(1, 0);
    BARRIER();                       // all waves done reading buf0
    STAGE_B(0, ta, 0); STAGE_B(1, ta, 0); STAGE_A(0, ta, 0); STAGE_A(1, ta, 0);
    VMWN();                          // t1 landed (issued a half-iter ago)
    BARRIER();
    // ---- second half: compute buf1 (t1), free-run ----
    LOAD_A(1, 0); LOAD_B(1, 0); MFMA_Q(0, 0);
    LOAD_B(1, 1);               MFMA_Q(0, 1);
    LOAD_A(1, 1);               MFMA_Q(1, 1);
                                MFMA_Q(1, 0);
    BARRIER();                       // all waves done reading buf1
    STAGE_B(0, tb, 1); STAGE_B(1, tb, 1); STAGE_A(0, tb, 1); STAGE_A(1, tb, 1);
    VMWN();                          // ta landed
    BARRIER();
  }
  asm volatile("s_waitcnt vmcnt(0)" ::: "memory");

  // ---- epilogues ----  C/D frag: col = fr, row = fs*4 + jj
  const int r0 = mbase + wm * WROWS;
  const int c0 = nbase + wn * 64;

  if constexpr (MODE == MODE_PROJ) {
    BARRIER();   // every wave has drained its DMAs -> LDS reusable
    char* ep = smem + w * AHB;
    if (z < 2) {   // row-major bf16 with bias+scale, coalesced via LDS restage
      bf16_t* o = (bf16_t*)outp + (size_t)z * strO;
      const float* bias = (z == 0) ? x0 : x1;
      const float scale = (z == 0) ? 0.03125f : 1.0f;
#pragma unroll
      for (int nf = 0; nf < 4; ++nf) {
        float bv = bias[c0 + nf * 16 + fr];
#pragma unroll
        for (int mf = 0; mf < MFR; ++mf)
#pragma unroll
          for (int jj = 0; jj < 4; ++jj) {
            int row = mf * 16 + fs * 4 + jj;
            int slot = (nf * 2 + (fr >> 3)) ^ ((row >> 1) & 7);
            *(bf16_t*)(ep + row * 128 + slot * 16 + (fr & 7) * 2) =
                f2bf((acc[mf][nf][jj] + bv) * scale);
          }
      }
      LGKM0();
      const int rl = lane >> 3, sl = lane & 7;
#pragma unroll
      for (int i = 0; i < WROWS / 8; ++i) {
        int row = i * 8 + rl;
        int slot = sl ^ ((row >> 1) & 7);
        uint4 vv = *(const uint4*)(ep + row * 128 + slot * 16);
        *(uint4*)&o[(size_t)(r0 + row) * ldo + c0 + sl * 8] = vv;
      }
    } else {   // z==2: VW + c2 -> VWt[b][c][r] transposed, coalesced
      bf16_t* ob = (bf16_t*)auxp;
      const int bidx = r0 >> 11, rb = r0 & (L_ - 1);
      ob += (size_t)bidx * D_ * L_;
#pragma unroll
      for (int nf = 0; nf < 4; ++nf) {
        int coll = nf * 16 + fr;
        float bv = x2[c0 + coll];
        int xm = (coll & (WROWS / 8 - 1)) << 3;
#pragma unroll
        for (int mf = 0; mf < MFR; ++mf) {
          int rbase = mf * 16 + fs * 4;
          union { bf16_t h[4]; uint2 u; } pk;
#pragma unroll
          for (int jj = 0; jj < 4; ++jj) pk.h[jj] = f2bf(acc[mf][nf][jj] + bv);
          *(uint2*)(ep + coll * (WROWS * 2) + 2 * (rbase ^ xm)) = pk.u;
        }
      }
      LGKM0();
      constexpr int LPC = WROWS / 8;
      constexpr int CPI = 64 / LPC;
      const int colr = lane / LPC;
      const int rc = (lane % LPC) * 8;
#pragma unroll
      for (int i2 = 0; i2 < LPC; ++i2) {
        int coll = i2 * CPI + colr;
        int xm = (coll & (WROWS / 8 - 1)) << 3;
        uint4 vv = *(const uint4*)(ep + coll * (WROWS * 2) + 2 * (rc ^ xm));
        *(uint4*)&ob[(size_t)(c0 + coll) * L_ + rb + rc] = vv;
      }
    }
  } else if constexpr (MODE == MODE_TRK) {   // fp32 K-split partials, direct
    float* o = (float*)outp + (size_t)z * strO;
#pragma unroll
    for (int mf = 0; mf < MFR; ++mf) {
#pragma unroll
      for (int jj = 0; jj < 4; ++jj) {
        int r = r0 + mf * 16 + fs * 4 + jj;
#pragma unroll
        for (int nf = 0; nf < 4; ++nf)
          o[(size_t)r * ldo + c0 + nf * 16 + fr] = acc[mf][nf][jj];
      }
    }
  } else if constexpr (MODE == MODE_S) {
    BARRIER();
    char* ep = smem + w * AHB;
    bf16_t* o = (bf16_t*)outp + (size_t)z * strO;
    const unsigned long long* bw =
        (const unsigned long long*)auxp +
        ((size_t)z * L_ + r0) * 32 + (c0 >> 6);
#pragma unroll
    for (int mf = 0; mf < MFR; ++mf) {
#pragma unroll
      for (int jj = 0; jj < 4; ++jj) {
        int row = mf * 16 + fs * 4 + jj;
        unsigned long long wd = bw[(size_t)row * 32];
        float psum = 0.f;
#pragma unroll
        for (int nf = 0; nf < 4; ++nf) {
          int cbit = nf * 16 + fr;
          float e = ((wd >> cbit) & 1ull) ? __expf(acc[mf][nf][jj]) : 0.0f;
          bf16_t eb = f2bf(e);
          psum += bf2f(eb);
          int slot = (nf * 2 + (fr >> 3)) ^ ((row >> 1) & 7);
          *(bf16_t*)(ep + row * 128 + slot * 16 + (fr & 7) * 2) = eb;
        }
#pragma unroll
        for (int off = 8; off; off >>= 1) psum += __shfl_xor(psum, off, 16);
        if (fr == 0)
          rsp[((size_t)z * L_ + r0 + row) * 32 + xb * 4 + wn] = psum;
      }
    }
    LGKM0();
    const int rl = lane >> 3, sl = lane & 7;
#pragma unroll
    for (int i = 0; i < WROWS / 8; ++i) {
      int row = i * 8 + rl;
      int slot = sl ^ ((row >> 1) & 7);
      uint4 vv = *(const uint4*)(ep + row * 128 + slot * 16);
      *(uint4*)&o[(size_t)(r0 + row) * ldo + c0 + sl * 8] = vv;
    }
  } else {  // MODE_FIN — fp32 direct
    float* o = (float*)outp + (size_t)z * strO;
    const float* rs = x0 + (size_t)z * L_;
#pragma unroll
    for (int mf = 0; mf < MFR; ++mf) {
#pragma unroll
      for (int jj = 0; jj < 4; ++jj) {
        int r = r0 + mf * 16 + fs * 4 + jj;
        float inv = 1.0f / rs[r];
#pragma unroll
        for (int nf = 0; nf < 4; ++nf) {
          int c = c0 + nf * 16 + fr;
          o[(size_t)r * ldo + c] = acc[mf][nf][jj] * inv + x1[c];
        }
      }
    }
  }
#undef STAGE_A
#undef STAGE_B
#undef LOAD_A
#undef LOAD_B
#undef MFMA_Q
#undef VMWN
#undef LGKM0
}

extern "C" void kernel_launch(void* const* d_in, const int* in_sizes, int n_in,
                              void* d_out, int out_size, void* d_ws, size_t ws_size,
                              hipStream_t stream) {
  const float* query = (const float*)d_in[0];
  const float* keyi  = (const float*)d_in[1];
  const float* value = (const float*)d_in[2];
  const int*   mask  = (const int*)d_in[3];
  const float* Wq = (const float*)d_in[4];
  const float* bq = (const float*)d_in[5];
  const float* Wk = (const float*)d_in[6];
  const float* bk = (const float*)d_in[7];
  const float* Wv = (const float*)d_in[8];
  const float* bv = (const float*)d_in[9];
  const float* Wo = (const float*)d_in[10];
  const float* bo = (const float*)d_in[11];

  bf16_t* ws = (bf16_t*)d_ws;
  bf16_t* XQ   = ws;                  // XQ,XK,XV contiguous (PROJ A z-stride)
  bf16_t* XK   = ws + NE_;
  bf16_t* XV   = ws + 2 * NE_;
  bf16_t* WQT  = ws + 3 * NE_;        // WQT,WKT,W2T contiguous (PROJ B z-stride)
  bf16_t* WKT  = WQT + WE_;
  bf16_t* W2T  = WKT + WE_;
  bf16_t* WOT  = W2T + WE_;
  bf16_t* WVb  = WOT + WE_;
  bf16_t* Qb   = WVb + WE_;           // Qb,Kb contiguous (PROJ out z-stride)
  bf16_t* Kb   = Qb + NE_;
  bf16_t* VWt  = Kb + NE_;            // (B) x (D, L), written by PROJ z=2
  float*  rsump= (float*)(VWt + NE_);               // (B*L)
  float*  c2p  = rsump + (size_t)B_ * L_;           // (1024)
  float*  rspart = c2p + D_;                        // (B*L, 32)
  unsigned long long* bmask =
      (unsigned long long*)(rspart + (size_t)B_ * L_ * 32);  // (B*L*L/64)
  bf16_t* Sb   = ws;                  // S/P (B,L,L) overlaps XQ+XK (dead after PROJ)
  float*  pW2  = (float*)Qb;          // 8xWE_ fp32 = 32MB, overlaps Qb+Kb
                                      // (dead before PROJ writes Qb)

  hipFuncSetAttribute((const void*)g8<128, MODE_PROJ>,
                      hipFuncAttributeMaxDynamicSharedMemorySize, 98304);
  hipFuncSetAttribute((const void*)g8<256, MODE_S>,
                      hipFuncAttributeMaxDynamicSharedMemorySize, 131072);
  hipFuncSetAttribute((const void*)g8<128, MODE_TRK>,
                      hipFuncAttributeMaxDynamicSharedMemorySize, 98304);
  hipFuncSetAttribute((const void*)g8<128, MODE_FIN>,
                      hipFuncAttributeMaxDynamicSharedMemorySize, 98304);

  // 1) prep: converts + mask pack + weight transposes (+Wv cvt) + c2
  prep_cvt<<<dim3(12288), dim3(256), 0, stream>>>(query, keyi, value, XQ);
  pack_mask<<<dim3(65536), dim3(256), 0, stream>>>(mask, bmask);
  transpose_cvt4<<<dim3(32, 32, 4), dim3(32, 8), 0, stream>>>(Wq, Wk, Wo, Wv, WQT);
  c2_kernel<<<dim3(4), dim3(256), 0, stream>>>(bv, Wo, c2p);
  // 2) W2 = Wv.Wo via K-split-8 (full 256-block round), fp32 partials -> reduce
  g8<128, MODE_TRK><<<dim3(4, 8, 8), 512, 98304, stream>>>(
      WVb, D_, 128, WOT, D_, 128, pW2, (long)WE_, D_,
      nullptr, nullptr, nullptr, nullptr, nullptr, 128);
  w2_reduce<<<dim3(32, 32), dim3(32, 8), 0, stream>>>(pW2, W2T);
  // 3) batched projections, BM=128 -> grid 768 = 3 exact CU-rounds
  g8<128, MODE_PROJ><<<dim3(4, 64, 3), 512, 98304, stream>>>(
      XQ, D_, (long)NE_, WQT, D_, (long)WE_, Qb, (long)NE_, D_,
      bq, bk, c2p, VWt, nullptr, D_);
  // 4) S = Q K^T fused with masked exp -> P (bf16) + partial rowsums
  g8<256, MODE_S><<<dim3(8, 8, 4), 512, 131072, stream>>>(
      Qb, D_, (long)L_ * D_, Kb, D_, (long)L_ * D_, Sb, (long)L_ * L_, L_,
      nullptr, nullptr, nullptr, bmask, rspart, D_);
  // 5) reduce partial rowsums
  reduce_rsum<<<dim3(32), dim3(256), 0, stream>>>(rspart, rsump);
  // 6) out = (P . VWt^T)/rs + bo  -> fp32 d_out
  g8<128, MODE_FIN><<<dim3(4, 16, 4), 512, 98304, stream>>>(
      Sb, L_, (long)L_ * L_, VWt, L_, (long)D_ * L_, d_out, (long)L_ * D_, D_,
      rsump, bo, nullptr, nullptr, nullptr, L_);
}

// Round 13
// 258.801 us; speedup vs baseline: 1.1488x; 1.0324x over previous
//
#include <hip/hip_runtime.h>

#define B_ 4
#define L_ 2048
#define D_ 1024
#define M_FLAT (B_*L_)   // 8192
#define NE_ ((size_t)M_FLAT * D_)   // 8388608
#define WE_ ((size_t)D_ * D_)       // 1048576

typedef unsigned short bf16_t;
typedef __attribute__((ext_vector_type(8))) short bf16x8;
typedef __attribute__((ext_vector_type(4))) float f32x4;

__device__ __forceinline__ bf16_t f2bf(float f) {
  union { float f; unsigned int u; } c; c.f = f;
  unsigned int u = c.u;
  unsigned int r = (u + 0x7fffu + ((u >> 16) & 1u)) >> 16;
  return (bf16_t)r;
}
__device__ __forceinline__ float bf2f(bf16_t h) {
  union { unsigned int u; float f; } c; c.u = ((unsigned int)h) << 16;
  return c.f;
}

__device__ __forceinline__ void gload_lds16(const bf16_t* g, bf16_t* l) {
  __builtin_amdgcn_global_load_lds(
      (const __attribute__((address_space(1))) unsigned int*)g,
      (__attribute__((address_space(3))) unsigned int*)l, 16, 0, 0);
}

#define BARRIER() do { asm volatile("" ::: "memory"); \
                       __builtin_amdgcn_s_barrier();  \
                       asm volatile("" ::: "memory"); } while (0)

// ================= merged prep kernel =================
// block ranges: [0,12288) q/k/v fp32->bf16 cvt; [12288,77824) mask bit-pack;
// [77824,81920) weight transposes (Wq,Wk,Wo) + Wv straight cvt; [81920,81924) c2.
__global__ __launch_bounds__(256) void prep_all(
    const float* __restrict__ q, const float* __restrict__ k,
    const float* __restrict__ v, const int* __restrict__ mask,
    const float* __restrict__ Wq, const float* __restrict__ Wk,
    const float* __restrict__ Wo, const float* __restrict__ Wv,
    const float* __restrict__ bv,
    bf16_t* __restrict__ outbase,      // WQT (WKT/W2T/WOT/WVb follow)
    bf16_t* __restrict__ xq,           // XQ (XK/XV follow)
    unsigned long long* __restrict__ bm,
    float* __restrict__ c2) {
  __shared__ float t[32][33];
  const int b = blockIdx.x, tid = threadIdx.x;
  if (b < 12288) {              // ---- q/k/v convert, 8 elts/thread ----
    const float* in; bf16_t* out; size_t li;
    if (b < 4096)      { in = q; out = xq;           li = (size_t)b * 256 + tid; }
    else if (b < 8192) { in = k; out = xq + NE_;     li = (size_t)(b - 4096) * 256 + tid; }
    else               { in = v; out = xq + 2 * NE_; li = (size_t)(b - 8192) * 256 + tid; }
    const float4* p = (const float4*)in + li * 2;
    float4 a = p[0], bb = p[1];
    union { bf16_t h[8]; uint4 u; } r;
    r.h[0] = f2bf(a.x); r.h[1] = f2bf(a.y); r.h[2] = f2bf(a.z); r.h[3] = f2bf(a.w);
    r.h[4] = f2bf(bb.x); r.h[5] = f2bf(bb.y); r.h[6] = f2bf(bb.z); r.h[7] = f2bf(bb.w);
    ((uint4*)out)[li] = r.u;
  } else if (b < 77824) {       // ---- mask pack: 64 ints -> u64 via ballot ----
    size_t gid = (size_t)(b - 12288) * 256 + tid;
    int mi = mask[gid];
    unsigned long long bb = __ballot(mi != 0);
    if ((tid & 63) == 0) bm[gid >> 6] = bb;
  } else if (b < 81920) {       // ---- weight transposes + Wv cvt ----
    int bb = b - 77824;
    int zz = bb >> 10, rem = bb & 1023;
    int bx = rem & 31, by = rem >> 5;
    int tx = tid & 31, ty = tid >> 5;          // (32,8)
    int c0 = bx * 32, r0 = by * 32;
    if (zz == 3) {   // Wv -> WVb straight convert
      bf16_t* o = outbase + 4 * WE_;
#pragma unroll
      for (int i = 0; i < 4; i++) {
        size_t idx = (size_t)(r0 + ty + i * 8) * D_ + c0 + tx;
        o[idx] = f2bf(Wv[idx]);
      }
      return;
    }
    const float* Wsrc = (zz == 0) ? Wq : (zz == 1) ? Wk : Wo;
    bf16_t* Wt = outbase + (size_t)(zz == 2 ? 3 : zz) * WE_;  // WQT,WKT,[W2T],WOT
#pragma unroll
    for (int i = 0; i < 4; i++)
      t[ty + i * 8][tx] = Wsrc[(size_t)(r0 + ty + i * 8) * D_ + c0 + tx];
    __syncthreads();
#pragma unroll
    for (int i = 0; i < 4; i++)
      Wt[(size_t)(c0 + ty + i * 8) * D_ + r0 + tx] = f2bf(t[tx][ty + i * 8]);
  } else {                      // ---- c2 = bv . Wo ----
    int j = (b - 81920) * 256 + tid;
    float s = 0.f;
    for (int kk = 0; kk < D_; kk++) s += bv[kk] * Wo[(size_t)kk * D_ + j];
    c2[j] = s;
  }
}

// ---- sum 8 fp32 K-split partials of W2, transpose+cvt -> W2T bf16 ----
__global__ __launch_bounds__(256) void w2_reduce(const float* __restrict__ pw,
                                                 bf16_t* __restrict__ w2t) {
  __shared__ float t[32][33];
  int c0 = blockIdx.x * 32, r0 = blockIdx.y * 32;
  int tx = threadIdx.x, ty = threadIdx.y;   // block (32,8)
#pragma unroll
  for (int i = 0; i < 4; i++) {
    size_t idx = (size_t)(r0 + ty + i * 8) * D_ + c0 + tx;
    float s = 0.f;
#pragma unroll
    for (int zz = 0; zz < 8; zz++) s += pw[(size_t)zz * WE_ + idx];
    t[ty + i * 8][tx] = s;
  }
  __syncthreads();
#pragma unroll
  for (int i = 0; i < 4; i++)
    w2t[(size_t)(c0 + ty + i * 8) * D_ + r0 + tx] = f2bf(t[tx][ty + i * 8]);
}

// ============ BMx256 BK=64 GEMM, free-running halves + counted vmcnt =========
// (r12-proven structure.)  MODE_FIN folds the 32-partial rowsum reduce into
// its prologue: 2KB LDS slot beyond both staging buffers.
#define MODE_PROJ 0  // z=0: Q=(acc+bq)/32; z=1: K=acc+bk; z=2: VW+c2 -> VWt (transposed)
#define MODE_S    1  // P = maskbit ? exp(acc) : 0 (bf16) + partial rowsums
#define MODE_FIN  2  // fp32 out = acc/rs[r] + bias[c]  (rs from partials, in-kernel)
#define MODE_TRK  3  // K-split fp32 partials (W2), z = K-chunk via strA/strB=128

template <int BM, int MODE>
__global__ __launch_bounds__(512, 2)
void g8(const bf16_t* __restrict__ Abase, int lda, long strA,
        const bf16_t* __restrict__ Bbase, int ldb, long strB,
        void* __restrict__ outp, long strO, int ldo,
        const float* __restrict__ x0, const float* __restrict__ x1,
        const float* __restrict__ x2,
        const void* __restrict__ auxp, float* __restrict__ rsp,
        int K) {
  constexpr int WROWS = BM / 2;        // per m-wave rows
  constexpr int QAF   = WROWS / 32;    // frag-rows per A-quadrant
  constexpr int MFR   = WROWS / 16;    // acc rows
  constexpr int AL    = BM / 128;      // gloads per A-half
  constexpr int BL    = 2;             // gloads per B-half
  constexpr int AHB   = WROWS * 128;   // bytes per A-half (= per-wave epi tile)
  constexpr int BUFB  = (BM + 256) * 128;
  extern __shared__ __align__(16) char smem[];

  const int tid = threadIdx.x, lane = tid & 63, w = tid >> 6;
  const int wm = w >> 2, wn = w & 3;
  const int fr = lane & 15, fs = lane >> 4;
  const int z = blockIdx.z;

  // XCD-chunk swizzle over (x,y) plane; z untouched
  int gx = gridDim.x, nxy = gx * gridDim.y;
  int lin = blockIdx.y * gx + blockIdx.x;
  if ((nxy & 7) == 0) { int q = nxy >> 3; lin = (lin & 7) * q + (lin >> 3); }
  const int xb = lin % gx;
  const int mbase = (lin / gx) * BM, nbase = xb * 256;

  const bf16_t* A  = Abase + (size_t)z * strA;
  const bf16_t* Bt = Bbase + (size_t)z * strB;

  int offA[2][2], offB[2][2];
#pragma unroll
  for (int h = 0; h < 2; h++)
#pragma unroll
    for (int i = 0; i < 2; i++) {
      int c = i * 512 + tid, row = c >> 3;
      int sg = (c & 7) ^ (row & 7);
      if (i < AL) offA[h][i] = (mbase + h * WROWS + row) * lda + sg * 8;
      offB[h][i] = (nbase + h * 128 + row) * ldb + sg * 8;
    }

  const int swz0 = (fs ^ (fr & 7)) * 16;
  const int swz1 = ((4 + fs) ^ (fr & 7)) * 16;

  bf16x8 af[QAF][2], bfv[2][2][2];
  f32x4 acc[MFR][4] = {};

#define STAGE_A(h, kt, bsel) do {                                             \
    char* hb_ = smem + (bsel) * BUFB + (h) * AHB;                             \
    _Pragma("unroll")                                                         \
    for (int i_ = 0; i_ < AL; ++i_)                                           \
      gload_lds16(A + offA[h][i_] + (kt) * 64,                                \
                  (bf16_t*)(hb_ + (i_ * 512 + tid) * 16));                    \
  } while (0)
#define STAGE_B(h, kt, bsel) do {                                             \
    char* hb_ = smem + (bsel) * BUFB + BM * 128 + (h) * 16384;                \
    _Pragma("unroll")                                                         \
    for (int i_ = 0; i_ < BL; ++i_)                                           \
      gload_lds16(Bt + offB[h][i_] + (kt) * 64,                               \
                  (bf16_t*)(hb_ + (i_ * 512 + tid) * 16));                    \
  } while (0)
#define LOAD_A(bsel, mh) do {                                                 \
    const char* ab_ = smem + (bsel) * BUFB + (wm * WROWS) * 128;              \
    _Pragma("unroll")                                                         \
    for (int i_ = 0; i_ < QAF; ++i_) {                                        \
      int rb_ = ((mh) * (WROWS / 2) + i_ * 16 + fr) * 128;                    \
      af[i_][0] = *(const bf16x8*)(ab_ + rb_ + swz0);                         \
      af[i_][1] = *(const bf16x8*)(ab_ + rb_ + swz1);                         \
    }                                                                         \
  } while (0)
#define LOAD_B(bsel, nh) do {                                                 \
    const char* bb_ = smem + (bsel) * BUFB + BM * 128 + (wn * 64) * 128;      \
    _Pragma("unroll")                                                         \
    for (int j_ = 0; j_ < 2; ++j_) {                                          \
      int rb_ = ((nh) * 32 + j_ * 16 + fr) * 128;                             \
      bfv[nh][j_][0] = *(const bf16x8*)(bb_ + rb_ + swz0);                    \
      bfv[nh][j_][1] = *(const bf16x8*)(bb_ + rb_ + swz1);                    \
    }                                                                         \
  } while (0)
#define MFMA_Q(mh, nh) do {                                                   \
    __builtin_amdgcn_s_setprio(1);                                            \
    _Pragma("unroll")                                                         \
    for (int i_ = 0; i_ < QAF; ++i_)                                          \
    _Pragma("unroll")                                                         \
    for (int j_ = 0; j_ < 2; ++j_) {                                          \
      acc[(mh)*QAF + i_][(nh)*2 + j_] = __builtin_amdgcn_mfma_f32_16x16x32_bf16( \
          af[i_][0], bfv[nh][j_][0], acc[(mh)*QAF + i_][(nh)*2 + j_], 0, 0, 0);  \
      acc[(mh)*QAF + i_][(nh)*2 + j_] = __builtin_amdgcn_mfma_f32_16x16x32_bf16( \
          af[i_][1], bfv[nh][j_][1], acc[(mh)*QAF + i_][(nh)*2 + j_], 0, 0, 0);  \
    }                                                                         \
    __builtin_amdgcn_s_setprio(0);                                            \
  } while (0)
// leave exactly the just-issued tile (4 + 2*AL instrs) outstanding
#define VMWN() do {                                                           \
    if constexpr (AL == 2) asm volatile("s_waitcnt vmcnt(8)" ::: "memory");   \
    else                   asm volatile("s_waitcnt vmcnt(6)" ::: "memory");   \
  } while (0)
#define LGKM0() asm volatile("s_waitcnt lgkmcnt(0)" ::: "memory")

  const int NK = K >> 6, NI = NK >> 1;

  // MODE_FIN: cooperative rowsum-partial reduce into LDS slot at 2*BUFB
  if constexpr (MODE == MODE_FIN) {
    float* rl = (float*)(smem + 2 * BUFB);     // [128 rows][4 quarters]
    int rrow = tid >> 2, rq = tid & 3;
    const float* rp = x0 + ((size_t)z * L_ + mbase + rrow) * 32 + rq * 8;
    float s_ = 0.f;
#pragma unroll
    for (int j_ = 0; j_ < 8; ++j_) s_ += rp[j_];
    rl[rrow * 4 + rq] = s_;
    LGKM0();   // drain own ds_write; prologue BARRIER publishes
  }

  // prologue: t0 -> buf0 ; t1 -> buf1 ; wait t0 landed (t1 in flight)
  STAGE_B(0, 0, 0); STAGE_B(1, 0, 0); STAGE_A(0, 0, 0); STAGE_A(1, 0, 0);
  STAGE_B(0, 1, 1); STAGE_B(1, 1, 1); STAGE_A(0, 1, 1); STAGE_A(1, 1, 1);
  VMWN(); BARRIER();

  for (int it = 0; it < NI; ++it) {
    const int ta = (2 * it + 2 < NK) ? 2 * it + 2 : NK - 1;
    const int tb = (2 * it + 3 < NK) ? 2 * it + 3 : NK - 1;
    // ---- first half: compute buf0 (t0), free-run ----
    LOAD_A(0, 0); LOAD_B(0, 0); MFMA_Q(0, 0);
    LOAD_B(0, 1);               MFMA_Q(0, 1);
    LOAD_A(0, 1);               MFMA_Q(1, 1);
                                MFMA_Q(1, 0);
    BARRIER();                       // all waves done reading buf0
    STAGE_B(0, ta, 0); STAGE_B(1, ta, 0); STAGE_A(0, ta, 0); STAGE_A(1, ta, 0);
    VMWN();                          // t1 landed (issued a half-iter ago)
    BARRIER();
    // ---- second half: compute buf1 (t1), free-run ----
    LOAD_A(1, 0); LOAD_B(1, 0); MFMA_Q(0, 0);
    LOAD_B(1, 1);               MFMA_Q(0, 1);
    LOAD_A(1, 1);               MFMA_Q(1, 1);
                                MFMA_Q(1, 0);
    BARRIER();                       // all waves done reading buf1
    STAGE_B(0, tb, 1); STAGE_B(1, tb, 1); STAGE_A(0, tb, 1); STAGE_A(1, tb, 1);
    VMWN();                          // ta landed
    BARRIER();
  }
  asm volatile("s_waitcnt vmcnt(0)" ::: "memory");

  // ---- epilogues ----  C/D frag: col = fr, row = fs*4 + jj
  const int r0 = mbase + wm * WROWS;
  const int c0 = nbase + wn * 64;

  if constexpr (MODE == MODE_PROJ) {
    BARRIER();   // every wave has drained its DMAs -> LDS reusable
    char* ep = smem + w * AHB;
    if (z < 2) {   // row-major bf16 with bias+scale, coalesced via LDS restage
      bf16_t* o = (bf16_t*)outp + (size_t)z * strO;
      const float* bias = (z == 0) ? x0 : x1;
      const float scale = (z == 0) ? 0.03125f : 1.0f;
#pragma unroll
      for (int nf = 0; nf < 4; ++nf) {
        float bv = bias[c0 + nf * 16 + fr];
#pragma unroll
        for (int mf = 0; mf < MFR; ++mf)
#pragma unroll
          for (int jj = 0; jj < 4; ++jj) {
            int row = mf * 16 + fs * 4 + jj;
            int slot = (nf * 2 + (fr >> 3)) ^ ((row >> 1) & 7);
            *(bf16_t*)(ep + row * 128 + slot * 16 + (fr & 7) * 2) =
                f2bf((acc[mf][nf][jj] + bv) * scale);
          }
      }
      LGKM0();
      const int rl = lane >> 3, sl = lane & 7;
#pragma unroll
      for (int i = 0; i < WROWS / 8; ++i) {
        int row = i * 8 + rl;
        int slot = sl ^ ((row >> 1) & 7);
        uint4 vv = *(const uint4*)(ep + row * 128 + slot * 16);
        *(uint4*)&o[(size_t)(r0 + row) * ldo + c0 + sl * 8] = vv;
      }
    } else {   // z==2: VW + c2 -> VWt[b][c][r] transposed, coalesced
      bf16_t* ob = (bf16_t*)auxp;
      const int bidx = r0 >> 11, rb = r0 & (L_ - 1);
      ob += (size_t)bidx * D_ * L_;
#pragma unroll
      for (int nf = 0; nf < 4; ++nf) {
        int coll = nf * 16 + fr;
        float bv = x2[c0 + coll];
        int xm = (coll & (WROWS / 8 - 1)) << 3;
#pragma unroll
        for (int mf = 0; mf < MFR; ++mf) {
          int rbase = mf * 16 + fs * 4;
          union { bf16_t h[4]; uint2 u; } pk;
#pragma unroll
          for (int jj = 0; jj < 4; ++jj) pk.h[jj] = f2bf(acc[mf][nf][jj] + bv);
          *(uint2*)(ep + coll * (WROWS * 2) + 2 * (rbase ^ xm)) = pk.u;
        }
      }
      LGKM0();
      constexpr int LPC = WROWS / 8;
      constexpr int CPI = 64 / LPC;
      const int colr = lane / LPC;
      const int rc = (lane % LPC) * 8;
#pragma unroll
      for (int i2 = 0; i2 < LPC; ++i2) {
        int coll = i2 * CPI + colr;
        int xm = (coll & (WROWS / 8 - 1)) << 3;
        uint4 vv = *(const uint4*)(ep + coll * (WROWS * 2) + 2 * (rc ^ xm));
        *(uint4*)&ob[(size_t)(c0 + coll) * L_ + rb + rc] = vv;
      }
    }
  } else if constexpr (MODE == MODE_TRK) {   // fp32 K-split partials, direct
    float* o = (float*)outp + (size_t)z * strO;
#pragma unroll
    for (int mf = 0; mf < MFR; ++mf) {
#pragma unroll
      for (int jj = 0; jj < 4; ++jj) {
        int r = r0 + mf * 16 + fs * 4 + jj;
#pragma unroll
        for (int nf = 0; nf < 4; ++nf)
          o[(size_t)r * ldo + c0 + nf * 16 + fr] = acc[mf][nf][jj];
      }
    }
  } else if constexpr (MODE == MODE_S) {
    BARRIER();
    char* ep = smem + w * AHB;
    bf16_t* o = (bf16_t*)outp + (size_t)z * strO;
    const unsigned long long* bw =
        (const unsigned long long*)auxp +
        ((size_t)z * L_ + r0) * 32 + (c0 >> 6);
#pragma unroll
    for (int mf = 0; mf < MFR; ++mf) {
#pragma unroll
      for (int jj = 0; jj < 4; ++jj) {
        int row = mf * 16 + fs * 4 + jj;
        unsigned long long wd = bw[(size_t)row * 32];
        float psum = 0.f;
#pragma unroll
        for (int nf = 0; nf < 4; ++nf) {
          int cbit = nf * 16 + fr;
          float e = ((wd >> cbit) & 1ull) ? __expf(acc[mf][nf][jj]) : 0.0f;
          bf16_t eb = f2bf(e);
          psum += bf2f(eb);
          int slot = (nf * 2 + (fr >> 3)) ^ ((row >> 1) & 7);
          *(bf16_t*)(ep + row * 128 + slot * 16 + (fr & 7) * 2) = eb;
        }
#pragma unroll
        for (int off = 8; off; off >>= 1) psum += __shfl_xor(psum, off, 16);
        if (fr == 0)
          rsp[((size_t)z * L_ + r0 + row) * 32 + xb * 4 + wn] = psum;
      }
    }
    LGKM0();
    const int rl = lane >> 3, sl = lane & 7;
#pragma unroll
    for (int i = 0; i < WROWS / 8; ++i) {
      int row = i * 8 + rl;
      int slot = sl ^ ((row >> 1) & 7);
      uint4 vv = *(const uint4*)(ep + row * 128 + slot * 16);
      *(uint4*)&o[(size_t)(r0 + row) * ldo + c0 + sl * 8] = vv;
    }
  } else {  // MODE_FIN — fp32 direct; rs from in-LDS partial sums
    float* o = (float*)outp + (size_t)z * strO;
    const float* rl = (const float*)(smem + 2 * BUFB);
#pragma unroll
    for (int mf = 0; mf < MFR; ++mf) {
#pragma unroll
      for (int jj = 0; jj < 4; ++jj) {
        int r = r0 + mf * 16 + fs * 4 + jj;
        int rloc = wm * WROWS + mf * 16 + fs * 4 + jj;
        float rsv = rl[rloc * 4] + rl[rloc * 4 + 1] +
                    rl[rloc * 4 + 2] + rl[rloc * 4 + 3];
        float inv = 1.0f / fmaxf(rsv, 1e-30f);
#pragma unroll
        for (int nf = 0; nf < 4; ++nf) {
          int c = c0 + nf * 16 + fr;
          o[(size_t)r * ldo + c] = acc[mf][nf][jj] * inv + x1[c];
        }
      }
    }
  }
#undef STAGE_A
#undef STAGE_B
#undef LOAD_A
#undef LOAD_B
#undef MFMA_Q
#undef VMWN
#undef LGKM0
}

extern "C" void kernel_launch(void* const* d_in, const int* in_sizes, int n_in,
                              void* d_out, int out_size, void* d_ws, size_t ws_size,
                              hipStream_t stream) {
  const float* query = (const float*)d_in[0];
  const float* keyi  = (const float*)d_in[1];
  const float* value = (const float*)d_in[2];
  const int*   mask  = (const int*)d_in[3];
  const float* Wq = (const float*)d_in[4];
  const float* bq = (const float*)d_in[5];
  const float* Wk = (const float*)d_in[6];
  const float* bk = (const float*)d_in[7];
  const float* Wv = (const float*)d_in[8];
  const float* bv = (const float*)d_in[9];
  const float* Wo = (const float*)d_in[10];
  const float* bo = (const float*)d_in[11];

  bf16_t* ws = (bf16_t*)d_ws;
  bf16_t* XQ   = ws;                  // XQ,XK,XV contiguous (PROJ A z-stride)
  bf16_t* XK   = ws + NE_;
  bf16_t* XV   = ws + 2 * NE_;
  bf16_t* WQT  = ws + 3 * NE_;        // WQT,WKT,W2T contiguous (PROJ B z-stride)
  bf16_t* WKT  = WQT + WE_;
  bf16_t* W2T  = WKT + WE_;
  bf16_t* WOT  = W2T + WE_;
  bf16_t* WVb  = WOT + WE_;
  bf16_t* Qb   = WVb + WE_;           // Qb,Kb contiguous (PROJ out z-stride)
  bf16_t* Kb   = Qb + NE_;
  bf16_t* VWt  = Kb + NE_;            // (B) x (D, L), written by PROJ z=2
  float*  c2p  = (float*)(VWt + NE_);               // (1024)
  float*  rspart = c2p + D_;                        // (B*L, 32)
  unsigned long long* bmask =
      (unsigned long long*)(rspart + (size_t)B_ * L_ * 32);  // (B*L*L/64)
  bf16_t* Sb   = ws;                  // S/P (B,L,L) overlaps XQ+XK (dead after PROJ)
  float*  pW2  = (float*)Qb;          // 8xWE_ fp32 = 32MB, overlaps Qb+Kb
                                      // (dead before PROJ writes Qb)

  hipFuncSetAttribute((const void*)g8<128, MODE_PROJ>,
                      hipFuncAttributeMaxDynamicSharedMemorySize, 98304);
  hipFuncSetAttribute((const void*)g8<256, MODE_S>,
                      hipFuncAttributeMaxDynamicSharedMemorySize, 131072);
  hipFuncSetAttribute((const void*)g8<128, MODE_TRK>,
                      hipFuncAttributeMaxDynamicSharedMemorySize, 98304);
  hipFuncSetAttribute((const void*)g8<128, MODE_FIN>,
                      hipFuncAttributeMaxDynamicSharedMemorySize, 100352);

  // 1) merged prep: q/k/v cvt + mask pack + weight transposes + Wv cvt + c2
  prep_all<<<dim3(81924), dim3(256), 0, stream>>>(
      query, keyi, value, mask, Wq, Wk, Wo, Wv, bv, WQT, XQ, bmask, c2p);
  // 2) W2 = Wv.Wo via K-split-8 (full 256-block round), fp32 partials -> reduce
  g8<128, MODE_TRK><<<dim3(4, 8, 8), 512, 98304, stream>>>(
      WVb, D_, 128, WOT, D_, 128, pW2, (long)WE_, D_,
      nullptr, nullptr, nullptr, nullptr, nullptr, 128);
  w2_reduce<<<dim3(32, 32), dim3(32, 8), 0, stream>>>(pW2, W2T);
  // 3) batched projections, BM=128 -> grid 768 = 3 exact CU-rounds
  g8<128, MODE_PROJ><<<dim3(4, 64, 3), 512, 98304, stream>>>(
      XQ, D_, (long)NE_, WQT, D_, (long)WE_, Qb, (long)NE_, D_,
      bq, bk, c2p, VWt, nullptr, D_);
  // 4) S = Q K^T fused with masked exp -> P (bf16) + partial rowsums
  g8<256, MODE_S><<<dim3(8, 8, 4), 512, 131072, stream>>>(
      Qb, D_, (long)L_ * D_, Kb, D_, (long)L_ * D_, Sb, (long)L_ * L_, L_,
      nullptr, nullptr, nullptr, bmask, rspart, D_);
  // 5) out = (P . VWt^T)/rs + bo  -> fp32 d_out  (rowsum reduce folded in)
  g8<128, MODE_FIN><<<dim3(4, 16, 4), 512, 100352, stream>>>(
      Sb, L_, (long)L_ * L_, VWt, L_, (long)D_ * L_, d_out, (long)L_ * D_, D_,
      rspart, bo, nullptr, nullptr, nullptr, L_);
}

// Round 14
// 215.401 us; speedup vs baseline: 1.3803x; 1.2015x over previous
//
#include <hip/hip_runtime.h>

#define B_ 4
#define L_ 2048
#define D_ 1024
#define M_FLAT (B_*L_)   // 8192
#define NE_ ((size_t)M_FLAT * D_)   // 8388608
#define WE_ ((size_t)D_ * D_)       // 1048576

typedef unsigned short bf16_t;
typedef __attribute__((ext_vector_type(8))) short bf16x8;
typedef __attribute__((ext_vector_type(4))) float f32x4;

__device__ __forceinline__ bf16_t f2bf(float f) {
  union { float f; unsigned int u; } c; c.f = f;
  unsigned int u = c.u;
  unsigned int r = (u + 0x7fffu + ((u >> 16) & 1u)) >> 16;
  return (bf16_t)r;
}
__device__ __forceinline__ float bf2f(bf16_t h) {
  union { unsigned int u; float f; } c; c.u = ((unsigned int)h) << 16;
  return c.f;
}

__device__ __forceinline__ void gload_lds16(const bf16_t* g, bf16_t* l) {
  __builtin_amdgcn_global_load_lds(
      (const __attribute__((address_space(1))) unsigned int*)g,
      (__attribute__((address_space(3))) unsigned int*)l, 16, 0, 0);
}

#define BARRIER() do { asm volatile("" ::: "memory"); \
                       __builtin_amdgcn_s_barrier();  \
                       asm volatile("" ::: "memory"); } while (0)

// ================= merged prep kernel =================
// block ranges: [0,12288) q/k/v fp32->bf16 cvt; [12288,28672) mask bit-pack
// (16B/thread); [28672,32768) weight transposes (Wq,Wk,Wo) + Wv cvt;
// [32768,32800) c2 k-split partials (reduced in w2_reduce).
__global__ __launch_bounds__(256) void prep_all(
    const float* __restrict__ q, const float* __restrict__ k,
    const float* __restrict__ v, const int* __restrict__ mask,
    const float* __restrict__ Wq, const float* __restrict__ Wk,
    const float* __restrict__ Wo, const float* __restrict__ Wv,
    const float* __restrict__ bv,
    bf16_t* __restrict__ outbase,      // WQT (WKT/W2T/WOT/WVb follow)
    bf16_t* __restrict__ xq,           // XQ (XK/XV follow)
    unsigned long long* __restrict__ bm,
    float* __restrict__ c2part) {
  __shared__ float t[32][33];
  const int b = blockIdx.x, tid = threadIdx.x;
  if (b < 12288) {              // ---- q/k/v convert, 8 elts/thread ----
    const float* in; bf16_t* out; size_t li;
    if (b < 4096)      { in = q; out = xq;           li = (size_t)b * 256 + tid; }
    else if (b < 8192) { in = k; out = xq + NE_;     li = (size_t)(b - 4096) * 256 + tid; }
    else               { in = v; out = xq + 2 * NE_; li = (size_t)(b - 8192) * 256 + tid; }
    const float4* p = (const float4*)in + li * 2;
    float4 a = p[0], bb = p[1];
    union { bf16_t h[8]; uint4 u; } r;
    r.h[0] = f2bf(a.x); r.h[1] = f2bf(a.y); r.h[2] = f2bf(a.z); r.h[3] = f2bf(a.w);
    r.h[4] = f2bf(bb.x); r.h[5] = f2bf(bb.y); r.h[6] = f2bf(bb.z); r.h[7] = f2bf(bb.w);
    ((uint4*)out)[li] = r.u;
  } else if (b < 28672) {       // ---- mask pack: 4 ints/thread, 4 ballots ----
    size_t base = (size_t)(b - 12288) * 1024;     // 1024 ints per block
    size_t wb = base + (size_t)(tid >> 6) * 256;  // per-wave 256 ints
    int lane = tid & 63;
    int m0 = mask[wb + lane];
    int m1 = mask[wb + 64 + lane];
    int m2 = mask[wb + 128 + lane];
    int m3 = mask[wb + 192 + lane];
    unsigned long long b0 = __ballot(m0 != 0);
    unsigned long long b1 = __ballot(m1 != 0);
    unsigned long long b2 = __ballot(m2 != 0);
    unsigned long long b3 = __ballot(m3 != 0);
    if (lane == 0) {
      size_t wo = wb >> 6;
      bm[wo] = b0; bm[wo + 1] = b1; bm[wo + 2] = b2; bm[wo + 3] = b3;
    }
  } else if (b < 32768) {       // ---- weight transposes + Wv cvt ----
    int bb = b - 28672;
    int zz = bb >> 10, rem = bb & 1023;
    int bx = rem & 31, by = rem >> 5;
    int tx = tid & 31, ty = tid >> 5;          // (32,8)
    int c0 = bx * 32, r0 = by * 32;
    if (zz == 3) {   // Wv -> WVb straight convert
      bf16_t* o = outbase + 4 * WE_;
#pragma unroll
      for (int i = 0; i < 4; i++) {
        size_t idx = (size_t)(r0 + ty + i * 8) * D_ + c0 + tx;
        o[idx] = f2bf(Wv[idx]);
      }
      return;
    }
    const float* Wsrc = (zz == 0) ? Wq : (zz == 1) ? Wk : Wo;
    bf16_t* Wt = outbase + (size_t)(zz == 2 ? 3 : zz) * WE_;  // WQT,WKT,[W2T],WOT
#pragma unroll
    for (int i = 0; i < 4; i++)
      t[ty + i * 8][tx] = Wsrc[(size_t)(r0 + ty + i * 8) * D_ + c0 + tx];
    __syncthreads();
#pragma unroll
    for (int i = 0; i < 4; i++)
      Wt[(size_t)(c0 + ty + i * 8) * D_ + r0 + tx] = f2bf(t[tx][ty + i * 8]);
  } else {                      // ---- c2 partials: 32 blocks (8 kc x 4 jb) ----
    int bb = b - 32768;
    int kc = bb >> 2, jb = bb & 3;
    int j = jb * 256 + tid;
    const float* wp = Wo + (size_t)(kc * 128) * D_ + j;
    const float* bp = bv + kc * 128;
    float s = 0.f;
#pragma unroll 8
    for (int kk = 0; kk < 128; kk++) s += bp[kk] * wp[(size_t)kk * D_];
    c2part[kc * D_ + j] = s;
  }
}

// ---- sum 8 fp32 K-split partials of W2, transpose+cvt -> W2T bf16;
//      also reduce the 8 c2 partials -> c2 (blocks with by==0) ----
__global__ __launch_bounds__(256) void w2_reduce(const float* __restrict__ pw,
                                                 bf16_t* __restrict__ w2t,
                                                 const float* __restrict__ c2part,
                                                 float* __restrict__ c2) {
  __shared__ float t[32][33];
  int c0 = blockIdx.x * 32, r0 = blockIdx.y * 32;
  int tx = threadIdx.x, ty = threadIdx.y;   // block (32,8)
#pragma unroll
  for (int i = 0; i < 4; i++) {
    size_t idx = (size_t)(r0 + ty + i * 8) * D_ + c0 + tx;
    float s = 0.f;
#pragma unroll
    for (int zz = 0; zz < 8; zz++) s += pw[(size_t)zz * WE_ + idx];
    t[ty + i * 8][tx] = s;
  }
  __syncthreads();
#pragma unroll
  for (int i = 0; i < 4; i++)
    w2t[(size_t)(c0 + ty + i * 8) * D_ + r0 + tx] = f2bf(t[tx][ty + i * 8]);
  if (blockIdx.y == 0 && ty == 0) {
    int c = c0 + tx;
    float s = 0.f;
#pragma unroll
    for (int kc = 0; kc < 8; kc++) s += c2part[kc * D_ + c];
    c2[c] = s;
  }
}

// ============ BMx256 BK=64 GEMM, free-running halves + counted vmcnt =========
// (r13-proven structure, unchanged.)
#define MODE_PROJ 0  // z=0: Q=(acc+bq)/32; z=1: K=acc+bk; z=2: VW+c2 -> VWt (transposed)
#define MODE_S    1  // P = maskbit ? exp(acc) : 0 (bf16) + partial rowsums
#define MODE_FIN  2  // fp32 out = acc/rs[r] + bias[c]  (rs from partials, in-kernel)
#define MODE_TRK  3  // K-split fp32 partials (W2), z = K-chunk via strA/strB=128

template <int BM, int MODE>
__global__ __launch_bounds__(512, 2)
void g8(const bf16_t* __restrict__ Abase, int lda, long strA,
        const bf16_t* __restrict__ Bbase, int ldb, long strB,
        void* __restrict__ outp, long strO, int ldo,
        const float* __restrict__ x0, const float* __restrict__ x1,
        const float* __restrict__ x2,
        const void* __restrict__ auxp, float* __restrict__ rsp,
        int K) {
  constexpr int WROWS = BM / 2;        // per m-wave rows
  constexpr int QAF   = WROWS / 32;    // frag-rows per A-quadrant
  constexpr int MFR   = WROWS / 16;    // acc rows
  constexpr int AL    = BM / 128;      // gloads per A-half
  constexpr int BL    = 2;             // gloads per B-half
  constexpr int AHB   = WROWS * 128;   // bytes per A-half (= per-wave epi tile)
  constexpr int BUFB  = (BM + 256) * 128;
  extern __shared__ __align__(16) char smem[];

  const int tid = threadIdx.x, lane = tid & 63, w = tid >> 6;
  const int wm = w >> 2, wn = w & 3;
  const int fr = lane & 15, fs = lane >> 4;
  const int z = blockIdx.z;

  // XCD-chunk swizzle over (x,y) plane; z untouched
  int gx = gridDim.x, nxy = gx * gridDim.y;
  int lin = blockIdx.y * gx + blockIdx.x;
  if ((nxy & 7) == 0) { int q = nxy >> 3; lin = (lin & 7) * q + (lin >> 3); }
  const int xb = lin % gx;
  const int mbase = (lin / gx) * BM, nbase = xb * 256;

  const bf16_t* A  = Abase + (size_t)z * strA;
  const bf16_t* Bt = Bbase + (size_t)z * strB;

  int offA[2][2], offB[2][2];
#pragma unroll
  for (int h = 0; h < 2; h++)
#pragma unroll
    for (int i = 0; i < 2; i++) {
      int c = i * 512 + tid, row = c >> 3;
      int sg = (c & 7) ^ (row & 7);
      if (i < AL) offA[h][i] = (mbase + h * WROWS + row) * lda + sg * 8;
      offB[h][i] = (nbase + h * 128 + row) * ldb + sg * 8;
    }

  const int swz0 = (fs ^ (fr & 7)) * 16;
  const int swz1 = ((4 + fs) ^ (fr & 7)) * 16;

  bf16x8 af[QAF][2], bfv[2][2][2];
  f32x4 acc[MFR][4] = {};

#define STAGE_A(h, kt, bsel) do {                                             \
    char* hb_ = smem + (bsel) * BUFB + (h) * AHB;                             \
    _Pragma("unroll")                                                         \
    for (int i_ = 0; i_ < AL; ++i_)                                           \
      gload_lds16(A + offA[h][i_] + (kt) * 64,                                \
                  (bf16_t*)(hb_ + (i_ * 512 + tid) * 16));                    \
  } while (0)
#define STAGE_B(h, kt, bsel) do {                                             \
    char* hb_ = smem + (bsel) * BUFB + BM * 128 + (h) * 16384;                \
    _Pragma("unroll")                                                         \
    for (int i_ = 0; i_ < BL; ++i_)                                           \
      gload_lds16(Bt + offB[h][i_] + (kt) * 64,                               \
                  (bf16_t*)(hb_ + (i_ * 512 + tid) * 16));                    \
  } while (0)
#define LOAD_A(bsel, mh) do {                                                 \
    const char* ab_ = smem + (bsel) * BUFB + (wm * WROWS) * 128;              \
    _Pragma("unroll")                                                         \
    for (int i_ = 0; i_ < QAF; ++i_) {                                        \
      int rb_ = ((mh) * (WROWS / 2) + i_ * 16 + fr) * 128;                    \
      af[i_][0] = *(const bf16x8*)(ab_ + rb_ + swz0);                         \
      af[i_][1] = *(const bf16x8*)(ab_ + rb_ + swz1);                         \
    }                                                                         \
  } while (0)
#define LOAD_B(bsel, nh) do {                                                 \
    const char* bb_ = smem + (bsel) * BUFB + BM * 128 + (wn * 64) * 128;      \
    _Pragma("unroll")                                                         \
    for (int j_ = 0; j_ < 2; ++j_) {                                          \
      int rb_ = ((nh) * 32 + j_ * 16 + fr) * 128;                             \
      bfv[nh][j_][0] = *(const bf16x8*)(bb_ + rb_ + swz0);                    \
      bfv[nh][j_][1] = *(const bf16x8*)(bb_ + rb_ + swz1);                    \
    }                                                                         \
  } while (0)
#define MFMA_Q(mh, nh) do {                                                   \
    __builtin_amdgcn_s_setprio(1);                                            \
    _Pragma("unroll")                                                         \
    for (int i_ = 0; i_ < QAF; ++i_)                                          \
    _Pragma("unroll")                                                         \
    for (int j_ = 0; j_ < 2; ++j_) {                                          \
      acc[(mh)*QAF + i_][(nh)*2 + j_] = __builtin_amdgcn_mfma_f32_16x16x32_bf16( \
          af[i_][0], bfv[nh][j_][0], acc[(mh)*QAF + i_][(nh)*2 + j_], 0, 0, 0);  \
      acc[(mh)*QAF + i_][(nh)*2 + j_] = __builtin_amdgcn_mfma_f32_16x16x32_bf16( \
          af[i_][1], bfv[nh][j_][1], acc[(mh)*QAF + i_][(nh)*2 + j_], 0, 0, 0);  \
    }                                                                         \
    __builtin_amdgcn_s_setprio(0);                                            \
  } while (0)
// leave exactly the just-issued tile (4 + 2*AL instrs) outstanding
#define VMWN() do {                                                           \
    if constexpr (AL == 2) asm volatile("s_waitcnt vmcnt(8)" ::: "memory");   \
    else                   asm volatile("s_waitcnt vmcnt(6)" ::: "memory");   \
  } while (0)
#define LGKM0() asm volatile("s_waitcnt lgkmcnt(0)" ::: "memory")

  const int NK = K >> 6, NI = NK >> 1;

  // MODE_FIN: cooperative rowsum-partial reduce into LDS slot at 2*BUFB
  if constexpr (MODE == MODE_FIN) {
    float* rl = (float*)(smem + 2 * BUFB);     // [128 rows][4 quarters]
    int rrow = tid >> 2, rq = tid & 3;
    const float* rp = x0 + ((size_t)z * L_ + mbase + rrow) * 32 + rq * 8;
    float s_ = 0.f;
#pragma unroll
    for (int j_ = 0; j_ < 8; ++j_) s_ += rp[j_];
    rl[rrow * 4 + rq] = s_;
    LGKM0();   // drain own ds_write; prologue BARRIER publishes
  }

  // prologue: t0 -> buf0 ; t1 -> buf1 ; wait t0 landed (t1 in flight)
  STAGE_B(0, 0, 0); STAGE_B(1, 0, 0); STAGE_A(0, 0, 0); STAGE_A(1, 0, 0);
  STAGE_B(0, 1, 1); STAGE_B(1, 1, 1); STAGE_A(0, 1, 1); STAGE_A(1, 1, 1);
  VMWN(); BARRIER();

  for (int it = 0; it < NI; ++it) {
    const int ta = (2 * it + 2 < NK) ? 2 * it + 2 : NK - 1;
    const int tb = (2 * it + 3 < NK) ? 2 * it + 3 : NK - 1;
    // ---- first half: compute buf0 (t0), free-run ----
    LOAD_A(0, 0); LOAD_B(0, 0); MFMA_Q(0, 0);
    LOAD_B(0, 1);               MFMA_Q(0, 1);
    LOAD_A(0, 1);               MFMA_Q(1, 1);
                                MFMA_Q(1, 0);
    BARRIER();                       // all waves done reading buf0
    STAGE_B(0, ta, 0); STAGE_B(1, ta, 0); STAGE_A(0, ta, 0); STAGE_A(1, ta, 0);
    VMWN();                          // t1 landed (issued a half-iter ago)
    BARRIER();
    // ---- second half: compute buf1 (t1), free-run ----
    LOAD_A(1, 0); LOAD_B(1, 0); MFMA_Q(0, 0);
    LOAD_B(1, 1);               MFMA_Q(0, 1);
    LOAD_A(1, 1);               MFMA_Q(1, 1);
                                MFMA_Q(1, 0);
    BARRIER();                       // all waves done reading buf1
    STAGE_B(0, tb, 1); STAGE_B(1, tb, 1); STAGE_A(0, tb, 1); STAGE_A(1, tb, 1);
    VMWN();                          // ta landed
    BARRIER();
  }
  asm volatile("s_waitcnt vmcnt(0)" ::: "memory");

  // ---- epilogues ----  C/D frag: col = fr, row = fs*4 + jj
  const int r0 = mbase + wm * WROWS;
  const int c0 = nbase + wn * 64;

  if constexpr (MODE == MODE_PROJ) {
    BARRIER();   // every wave has drained its DMAs -> LDS reusable
    char* ep = smem + w * AHB;
    if (z < 2) {   // row-major bf16 with bias+scale, coalesced via LDS restage
      bf16_t* o = (bf16_t*)outp + (size_t)z * strO;
      const float* bias = (z == 0) ? x0 : x1;
      const float scale = (z == 0) ? 0.03125f : 1.0f;
#pragma unroll
      for (int nf = 0; nf < 4; ++nf) {
        float bv = bias[c0 + nf * 16 + fr];
#pragma unroll
        for (int mf = 0; mf < MFR; ++mf)
#pragma unroll
          for (int jj = 0; jj < 4; ++jj) {
            int row = mf * 16 + fs * 4 + jj;
            int slot = (nf * 2 + (fr >> 3)) ^ ((row >> 1) & 7);
            *(bf16_t*)(ep + row * 128 + slot * 16 + (fr & 7) * 2) =
                f2bf((acc[mf][nf][jj] + bv) * scale);
          }
      }
      LGKM0();
      const int rl = lane >> 3, sl = lane & 7;
#pragma unroll
      for (int i = 0; i < WROWS / 8; ++i) {
        int row = i * 8 + rl;
        int slot = sl ^ ((row >> 1) & 7);
        uint4 vv = *(const uint4*)(ep + row * 128 + slot * 16);
        *(uint4*)&o[(size_t)(r0 + row) * ldo + c0 + sl * 8] = vv;
      }
    } else {   // z==2: VW + c2 -> VWt[b][c][r] transposed, coalesced
      bf16_t* ob = (bf16_t*)auxp;
      const int bidx = r0 >> 11, rb = r0 & (L_ - 1);
      ob += (size_t)bidx * D_ * L_;
#pragma unroll
      for (int nf = 0; nf < 4; ++nf) {
        int coll = nf * 16 + fr;
        float bv = x2[c0 + coll];
        int xm = (coll & (WROWS / 8 - 1)) << 3;
#pragma unroll
        for (int mf = 0; mf < MFR; ++mf) {
          int rbase = mf * 16 + fs * 4;
          union { bf16_t h[4]; uint2 u; } pk;
#pragma unroll
          for (int jj = 0; jj < 4; ++jj) pk.h[jj] = f2bf(acc[mf][nf][jj] + bv);
          *(uint2*)(ep + coll * (WROWS * 2) + 2 * (rbase ^ xm)) = pk.u;
        }
      }
      LGKM0();
      constexpr int LPC = WROWS / 8;
      constexpr int CPI = 64 / LPC;
      const int colr = lane / LPC;
      const int rc = (lane % LPC) * 8;
#pragma unroll
      for (int i2 = 0; i2 < LPC; ++i2) {
        int coll = i2 * CPI + colr;
        int xm = (coll & (WROWS / 8 - 1)) << 3;
        uint4 vv = *(const uint4*)(ep + coll * (WROWS * 2) + 2 * (rc ^ xm));
        *(uint4*)&ob[(size_t)(c0 + coll) * L_ + rb + rc] = vv;
      }
    }
  } else if constexpr (MODE == MODE_TRK) {   // fp32 K-split partials, direct
    float* o = (float*)outp + (size_t)z * strO;
#pragma unroll
    for (int mf = 0; mf < MFR; ++mf) {
#pragma unroll
      for (int jj = 0; jj < 4; ++jj) {
        int r = r0 + mf * 16 + fs * 4 + jj;
#pragma unroll
        for (int nf = 0; nf < 4; ++nf)
          o[(size_t)r * ldo + c0 + nf * 16 + fr] = acc[mf][nf][jj];
      }
    }
  } else if constexpr (MODE == MODE_S) {
    BARRIER();
    char* ep = smem + w * AHB;
    bf16_t* o = (bf16_t*)outp + (size_t)z * strO;
    const unsigned long long* bw =
        (const unsigned long long*)auxp +
        ((size_t)z * L_ + r0) * 32 + (c0 >> 6);
#pragma unroll
    for (int mf = 0; mf < MFR; ++mf) {
#pragma unroll
      for (int jj = 0; jj < 4; ++jj) {
        int row = mf * 16 + fs * 4 + jj;
        unsigned long long wd = bw[(size_t)row * 32];
        float psum = 0.f;
#pragma unroll
        for (int nf = 0; nf < 4; ++nf) {
          int cbit = nf * 16 + fr;
          float e = ((wd >> cbit) & 1ull) ? __expf(acc[mf][nf][jj]) : 0.0f;
          bf16_t eb = f2bf(e);
          psum += bf2f(eb);
          int slot = (nf * 2 + (fr >> 3)) ^ ((row >> 1) & 7);
          *(bf16_t*)(ep + row * 128 + slot * 16 + (fr & 7) * 2) = eb;
        }
#pragma unroll
        for (int off = 8; off; off >>= 1) psum += __shfl_xor(psum, off, 16);
        if (fr == 0)
          rsp[((size_t)z * L_ + r0 + row) * 32 + xb * 4 + wn] = psum;
      }
    }
    LGKM0();
    const int rl = lane >> 3, sl = lane & 7;
#pragma unroll
    for (int i = 0; i < WROWS / 8; ++i) {
      int row = i * 8 + rl;
      int slot = sl ^ ((row >> 1) & 7);
      uint4 vv = *(const uint4*)(ep + row * 128 + slot * 16);
      *(uint4*)&o[(size_t)(r0 + row) * ldo + c0 + sl * 8] = vv;
    }
  } else {  // MODE_FIN — fp32 direct; rs from in-LDS partial sums
    float* o = (float*)outp + (size_t)z * strO;
    const float* rl = (const float*)(smem + 2 * BUFB);
#pragma unroll
    for (int mf = 0; mf < MFR; ++mf) {
#pragma unroll
      for (int jj = 0; jj < 4; ++jj) {
        int r = r0 + mf * 16 + fs * 4 + jj;
        int rloc = wm * WROWS + mf * 16 + fs * 4 + jj;
        float rsv = rl[rloc * 4] + rl[rloc * 4 + 1] +
                    rl[rloc * 4 + 2] + rl[rloc * 4 + 3];
        float inv = 1.0f / fmaxf(rsv, 1e-30f);
#pragma unroll
        for (int nf = 0; nf < 4; ++nf) {
          int c = c0 + nf * 16 + fr;
          o[(size_t)r * ldo + c] = acc[mf][nf][jj] * inv + x1[c];
        }
      }
    }
  }
#undef STAGE_A
#undef STAGE_B
#undef LOAD_A
#undef LOAD_B
#undef MFMA_Q
#undef VMWN
#undef LGKM0
}

extern "C" void kernel_launch(void* const* d_in, const int* in_sizes, int n_in,
                              void* d_out, int out_size, void* d_ws, size_t ws_size,
                              hipStream_t stream) {
  const float* query = (const float*)d_in[0];
  const float* keyi  = (const float*)d_in[1];
  const float* value = (const float*)d_in[2];
  const int*   mask  = (const int*)d_in[3];
  const float* Wq = (const float*)d_in[4];
  const float* bq = (const float*)d_in[5];
  const float* Wk = (const float*)d_in[6];
  const float* bk = (const float*)d_in[7];
  const float* Wv = (const float*)d_in[8];
  const float* bv = (const float*)d_in[9];
  const float* Wo = (const float*)d_in[10];
  const float* bo = (const float*)d_in[11];

  bf16_t* ws = (bf16_t*)d_ws;
  bf16_t* XQ   = ws;                  // XQ,XK,XV contiguous (PROJ A z-stride)
  bf16_t* XK   = ws + NE_;
  bf16_t* XV   = ws + 2 * NE_;
  bf16_t* WQT  = ws + 3 * NE_;        // WQT,WKT,W2T contiguous (PROJ B z-stride)
  bf16_t* WKT  = WQT + WE_;
  bf16_t* W2T  = WKT + WE_;
  bf16_t* WOT  = W2T + WE_;
  bf16_t* WVb  = WOT + WE_;
  bf16_t* Qb   = WVb + WE_;           // Qb,Kb contiguous (PROJ out z-stride)
  bf16_t* Kb   = Qb + NE_;
  bf16_t* VWt  = Kb + NE_;            // (B) x (D, L), written by PROJ z=2
  float*  c2p  = (float*)(VWt + NE_);               // (1024)
  float*  rspart = c2p + D_;                        // (B*L, 32)
  unsigned long long* bmask =
      (unsigned long long*)(rspart + (size_t)B_ * L_ * 32);  // (B*L*L/64)
  float*  c2part = (float*)(bmask + (size_t)B_ * L_ * L_ / 64);  // (8,1024)
  bf16_t* Sb   = ws;                  // S/P (B,L,L) overlaps XQ+XK (dead after PROJ)
  float*  pW2  = (float*)Qb;          // 8xWE_ fp32 = 32MB, overlaps Qb+Kb
                                      // (dead before PROJ writes Qb)

  hipFuncSetAttribute((const void*)g8<128, MODE_PROJ>,
                      hipFuncAttributeMaxDynamicSharedMemorySize, 98304);
  hipFuncSetAttribute((const void*)g8<256, MODE_S>,
                      hipFuncAttributeMaxDynamicSharedMemorySize, 131072);
  hipFuncSetAttribute((const void*)g8<128, MODE_TRK>,
                      hipFuncAttributeMaxDynamicSharedMemorySize, 98304);
  hipFuncSetAttribute((const void*)g8<128, MODE_FIN>,
                      hipFuncAttributeMaxDynamicSharedMemorySize, 100352);

  // 1) merged prep: q/k/v cvt + mask pack(16B/t) + weight transposes + c2 partials
  prep_all<<<dim3(32800), dim3(256), 0, stream>>>(
      query, keyi, value, mask, Wq, Wk, Wo, Wv, bv, WQT, XQ, bmask, c2part);
  // 2) W2 = Wv.Wo via K-split-8 (full 256-block round), fp32 partials -> reduce
  g8<128, MODE_TRK><<<dim3(4, 8, 8), 512, 98304, stream>>>(
      WVb, D_, 128, WOT, D_, 128, pW2, (long)WE_, D_,
      nullptr, nullptr, nullptr, nullptr, nullptr, 128);
  w2_reduce<<<dim3(32, 32), dim3(32, 8), 0, stream>>>(pW2, W2T, c2part, c2p);
  // 3) batched projections, BM=128 -> grid 768 = 3 exact CU-rounds
  g8<128, MODE_PROJ><<<dim3(4, 64, 3), 512, 98304, stream>>>(
      XQ, D_, (long)NE_, WQT, D_, (long)WE_, Qb, (long)NE_, D_,
      bq, bk, c2p, VWt, nullptr, D_);
  // 4) S = Q K^T fused with masked exp -> P (bf16) + partial rowsums
  g8<256, MODE_S><<<dim3(8, 8, 4), 512, 131072, stream>>>(
      Qb, D_, (long)L_ * D_, Kb, D_, (long)L_ * D_, Sb, (long)L_ * L_, L_,
      nullptr, nullptr, nullptr, bmask, rspart, D_);
  // 5) out = (P . VWt^T)/rs + bo  -> fp32 d_out  (rowsum reduce folded in)
  g8<128, MODE_FIN><<<dim3(4, 16, 4), 512, 100352, stream>>>(
      Sb, L_, (long)L_ * L_, VWt, L_, (long)D_ * L_, d_out, (long)L_ * D_, D_,
      rspart, bo, nullptr, nullptr, nullptr, L_);
}